// Round 6
// baseline (1787.599 us; speedup 1.0000x reference)
//
#include <hip/hip_runtime.h>
#include <math.h>

#define N_VARS 40000
#define FEAT 128
#define N_EDGES 200000
#define N_CONFP 100000
#define T_ITERS 3
#define EPSF 1e-5f

#define NB_CONF 782              // ceil(200000/256)
#define NB_LOSS 3517             // ceil(900000/256)
#define NB_STAT 157              // ceil(40000/256)
#define OUT_TOTAL 1120003
#define NCONF_SLOT 1120002       // sequential carve: 1+1+480000+600000+40000

// integer-bit NaN/Inf scrub (immune to fast-math): NaN/Inf -> 0
__device__ __forceinline__ float scrub0(float x){
  unsigned u = __float_as_uint(x);
  return ((u & 0x7F800000u) == 0x7F800000u) ? 0.f : x;
}

// ---- zero entire float output buffer ----
__global__ __launch_bounds__(256) void k_zero_out(float* __restrict__ out, int n){
  int i = blockIdx.x*256 + threadIdx.x;
  if (i < n) out[i] = 0.f;
}
// ---- zero agg: 5000*256 float4 == N_VARS*FEAT floats exactly ----
__global__ __launch_bounds__(256) void k_zero_agg(float4* __restrict__ p){
  p[blockIdx.x*256 + threadIdx.x] = make_float4(0.f,0.f,0.f,0.f);
}

// ---- PQ = x @ [W1top | W1bot]  (N x 256), fp32 ----
__global__ __launch_bounds__(256) void k_pq(const float* __restrict__ x,
                                            const float* __restrict__ W1,
                                            float* __restrict__ PQ){
  __shared__ float sA[16][FEAT];
  const int tid = threadIdx.x;
  const int row0 = blockIdx.x * 16;
#pragma unroll
  for (int i = 0; i < 8; ++i){
    int idx = tid + i*256;
    sA[idx >> 7][idx & 127] = x[row0*FEAT + idx];
  }
  __syncthreads();
  const int half_sel = tid >> 7;   // 0: W1 rows 0..127 (P), 1: rows 128..255 (Q)
  const int col  = tid & 127;
  float acc[16];
#pragma unroll
  for (int r = 0; r < 16; ++r) acc[r] = 0.f;
  const float* Wb = W1 + (half_sel*FEAT)*FEAT + col;
  for (int kq = 0; kq < FEAT/4; ++kq){
    float w0 = Wb[(kq*4+0)*FEAT];
    float w1 = Wb[(kq*4+1)*FEAT];
    float w2 = Wb[(kq*4+2)*FEAT];
    float w3 = Wb[(kq*4+3)*FEAT];
#pragma unroll
    for (int r = 0; r < 16; ++r){
      const float4 v = *(const float4*)&sA[r][kq*4];
      acc[r] = fmaf(v.x, w0, acc[r]);
      acc[r] = fmaf(v.y, w1, acc[r]);
      acc[r] = fmaf(v.z, w2, acc[r]);
      acc[r] = fmaf(v.w, w3, acc[r]);
    }
  }
#pragma unroll
  for (int r = 0; r < 16; ++r)
    PQ[(row0 + r)*2*FEAT + tid] = acc[r];
}

// ---- edge kernel: U = relu(P[b]+Q[a]+b1); Z = relu(U@W2 + b2); LN; scatter ----
__global__ __launch_bounds__(128) void k_edge(const float* __restrict__ PQ,
    const float* __restrict__ W2, const float* __restrict__ b1v,
    const float* __restrict__ b2v, const float* __restrict__ ln_g, const float* __restrict__ ln_b,
    const int* __restrict__ idxL, const int* __restrict__ idxR,
    float* __restrict__ agg){
  __shared__ float sU[16][FEAT];
  __shared__ int sTa[16], sTb[16];
  const int tid = threadIdx.x;
  const int m0 = blockIdx.x * 16;
  if (tid < 16){
    int m = m0 + tid;
    int e = (m < N_EDGES) ? m : (m - N_EDGES);
    int l = idxL[e], r = idxR[e];
    sTa[tid] = (m < N_EDGES) ? l : r;   // scatter target + Q row
    sTb[tid] = (m < N_EDGES) ? r : l;   // P row
  }
  __syncthreads();
  const float b1t = b1v[tid];
#pragma unroll
  for (int r = 0; r < 16; ++r){
    float u = PQ[sTb[r]*(2*FEAT) + tid] + PQ[sTa[r]*(2*FEAT) + FEAT + tid] + b1t;
    sU[r][tid] = fmaxf(u, 0.f);
  }
  __syncthreads();
  float acc[16];
#pragma unroll
  for (int r = 0; r < 16; ++r) acc[r] = 0.f;
  const float* Wb = W2 + tid;
  for (int kq = 0; kq < FEAT/4; ++kq){
    float w0 = Wb[(kq*4+0)*FEAT];
    float w1 = Wb[(kq*4+1)*FEAT];
    float w2 = Wb[(kq*4+2)*FEAT];
    float w3 = Wb[(kq*4+3)*FEAT];
#pragma unroll
    for (int r = 0; r < 16; ++r){
      const float4 v = *(const float4*)&sU[r][kq*4];
      acc[r] = fmaf(v.x, w0, acc[r]);
      acc[r] = fmaf(v.y, w1, acc[r]);
      acc[r] = fmaf(v.z, w2, acc[r]);
      acc[r] = fmaf(v.w, w3, acc[r]);
    }
  }
  const float b2t = b2v[tid];
#pragma unroll
  for (int r = 0; r < 16; ++r) acc[r] = fmaxf(acc[r] + b2t, 0.f);
  __syncthreads();
#pragma unroll
  for (int r = 0; r < 16; ++r) sU[r][tid] = acc[r];
  __syncthreads();
  const int w = tid >> 6, l = tid & 63;
  const float g0 = ln_g[l],  g1 = ln_g[l+64];
  const float be0 = ln_b[l], be1 = ln_b[l+64];
#pragma unroll
  for (int r8 = 0; r8 < 8; ++r8){
    int r = w*8 + r8;
    float v0 = sU[r][l], v1 = sU[r][l+64];
    float s = v0 + v1, q = v0*v0 + v1*v1;
#pragma unroll
    for (int o = 32; o > 0; o >>= 1){ s += __shfl_xor(s, o); q += __shfl_xor(q, o); }
    float mu = s * (1.f/FEAT);
    float var = fmaxf(q * (1.f/FEAT) - mu*mu, 0.f);
    float rv = rsqrtf(var + EPSF);
    int a = sTa[r];
    float o0 = scrub0(g0*(v0-mu)*rv + be0);
    float o1 = scrub0(g1*(v1-mu)*rv + be1);
    atomicAdd(&agg[a*FEAT + l],      o0);
    atomicAdd(&agg[a*FEAT + l + 64], o1);
  }
}

// ---- BN stats: per-block fp32 partial sum/sumsq of rec = agg/deg ----
__global__ __launch_bounds__(256) void k_stats(const float* __restrict__ agg,
    const float* __restrict__ degrees, float* __restrict__ red_part){
  const int tid = threadIdx.x;
  const int j = tid & 127, half_sel = tid >> 7;
  const int n0 = blockIdx.x * 256;
  float s1 = 0.f, s2 = 0.f;
  for (int i = half_sel; i < 256; i += 2){
    int n = n0 + i;
    if (n < N_VARS){
      float v = agg[n*FEAT + j] / degrees[n];
      s1 += v;
      s2 += v*v;
    }
  }
  __shared__ float sh1[256], sh2[256];
  sh1[tid] = s1; sh2[tid] = s2;
  __syncthreads();
  if (half_sel == 0){
    red_part[blockIdx.x*256 + j]       = sh1[tid] + sh1[tid+128];
    red_part[blockIdx.x*256 + 128 + j] = sh2[tid] + sh2[tid+128];
  }
}

// ---- reduce red_part -> red[256] (Kahan, single block, deterministic) ----
__global__ __launch_bounds__(256) void k_red(const float* __restrict__ red_part,
                                             float* __restrict__ red){
  const int tid = threadIdx.x;    // tid<128: sum(feature tid); tid>=128: sumsq(feature tid-128)
  float s = 0.f, c = 0.f;
  for (int b = 0; b < NB_STAT; ++b){
    float y = red_part[b*256 + tid] - c;
    float t = s + y;
    c = (t - s) - y;
    s = t;
  }
  red[tid] = s;
}

// ---- BN apply + logits + softmax + argmax; one wave per row ----
__global__ __launch_bounds__(256) void k_bn(const float* __restrict__ agg,
    const float* __restrict__ degrees, const float* __restrict__ red,
    const float* __restrict__ bn_g, const float* __restrict__ bn_b,
    const float* __restrict__ Wd, const float* __restrict__ bd,
    float* __restrict__ state, int* __restrict__ asg,
    float* __restrict__ out_phi, float* __restrict__ out_asg, int t){
  const int w = threadIdx.x >> 6, l = threadIdx.x & 63;
  const int n = blockIdx.x*4 + w;
  const float invN = 1.f / (float)N_VARS;
  float mu0 = red[l]*invN,     mu1 = red[l+64]*invN;
  float v0  = fmaxf(red[128+l]*invN    - mu0*mu0, 0.f);
  float v1  = fmaxf(red[128+l+64]*invN - mu1*mu1, 0.f);
  float rv0 = rsqrtf(v0 + EPSF);
  float rv1 = rsqrtf(v1 + EPSF);
  float dinv = 1.f / degrees[n];
  float r0 = agg[n*FEAT + l]    * dinv;
  float r1 = agg[n*FEAT + l+64] * dinv;
  float s0 = scrub0(bn_g[l]   *(r0 - mu0)*rv0 + bn_b[l]);
  float s1 = scrub0(bn_g[l+64]*(r1 - mu1)*rv1 + bn_b[l+64]);
  state[n*FEAT + l]    = s0;
  state[n*FEAT + l+64] = s1;
  float p[4];
#pragma unroll
  for (int d = 0; d < 4; ++d)
    p[d] = s0*Wd[l*4 + d] + s1*Wd[(l+64)*4 + d];
#pragma unroll
  for (int o = 32; o > 0; o >>= 1){
#pragma unroll
    for (int d = 0; d < 4; ++d) p[d] += __shfl_xor(p[d], o);
  }
  if (l == 0){
    float lg[4];
#pragma unroll
    for (int d = 0; d < 4; ++d) lg[d] = scrub0(p[d] + bd[d]);
    float mx = fmaxf(fmaxf(lg[0],lg[1]), fmaxf(lg[2],lg[3]));
    float ex[4]; float ssum = 0.f;
#pragma unroll
    for (int d = 0; d < 4; ++d){ ex[d] = expf(lg[d] - mx); ssum += ex[d]; }
    float inv = 1.f / ssum;
    int am = 0; float bv = -1.f;
#pragma unroll
    for (int d = 0; d < 4; ++d){
      float pv = scrub0(ex[d]*inv);
      out_phi[n*12 + t*4 + d] = pv;
      if (pv > bv){ bv = pv; am = d; }
    }
    asg[n*3 + t] = am;
    if (t == 2) out_asg[n] = (float)am;
  }
}

// ---- edge conflicts -> out_ec ----
__global__ __launch_bounds__(256) void k_conf(const int* __restrict__ asg,
    const int* __restrict__ idxL, const int* __restrict__ idxR,
    const float* __restrict__ relation, float* __restrict__ out_ec){
  const int e = blockIdx.x*256 + threadIdx.x;
  if (e < N_EDGES){
    int l = idxL[e], r = idxR[e];
#pragma unroll
    for (int tt = 0; tt < 3; ++tt){
      int ai = asg[l*3+tt] & 3, bi = asg[r*3+tt] & 3;
      out_ec[e*3 + tt] = scrub0(1.f - relation[ai*4 + bi]);
    }
  }
}

// ---- n_conf + conflict_ratio: single block, deterministic ----
__global__ __launch_bounds__(256) void k_nconf(const int* __restrict__ asg,
    const int* __restrict__ idxL, const int* __restrict__ idxR,
    const float* __restrict__ relation, float* __restrict__ out){
  const int tid = threadIdx.x;
  float rl[16];
#pragma unroll
  for (int i = 0; i < 16; ++i) rl[i] = relation[i];
  float s = 0.f;
  for (int e = tid; e < N_EDGES; e += 256){
    int l = idxL[e], r = idxR[e];
    int ai = asg[l*3+2] & 3, bi = asg[r*3+2] & 3;
    s += 1.f - rl[ai*4 + bi];
  }
  __shared__ float sh[256];
  sh[tid] = s;
  __syncthreads();
  for (int k = 128; k > 0; k >>= 1){
    if (tid < k) sh[tid] += sh[tid + k];
    __syncthreads();
  }
  if (tid == 0){
    float nc = sh[0];
    out[NCONF_SLOT] = nc;
    out[1] = nc / (float)N_EDGES;
  }
}

// ---- pair losses from fp32 phi (in d_out): per-block partials ----
__global__ __launch_bounds__(256) void k_loss(const float* __restrict__ phi,
    const int* __restrict__ iL, const int* __restrict__ iR,
    const int* __restrict__ iLp, const int* __restrict__ iRp,
    const float* __restrict__ rel, const float* __restrict__ conf,
    float* __restrict__ part_l1, float* __restrict__ part_l2){
  const int m = blockIdx.x*256 + threadIdx.x;
  float p1 = 0.f, p2 = 0.f;
  if (m < N_EDGES*3){
    int e = m/3, tt = m - e*3;
    const float* pl = phi + iL[e]*12 + tt*4;
    const float* pr = phi + iR[e]*12 + tt*4;
    float s = 0.f;
#pragma unroll
    for (int j = 0; j < 4; ++j){
      float tj = 0.f;
#pragma unroll
      for (int i = 0; i < 4; ++i) tj += pl[i]*rel[i*4+j];
      s += tj*pr[j];
    }
    s = scrub0(s); s = fmaxf(s, 1e-35f);
    p1 = -logf(s);
  } else {
    int m2 = m - N_EDGES*3;
    if (m2 < N_CONFP*3){
      int e = m2/3, tt = m2 - e*3;
      const float* pl = phi + iLp[e]*12 + tt*4;
      const float* pr = phi + iRp[e]*12 + tt*4;
      float s = 0.f;
#pragma unroll
      for (int j = 0; j < 4; ++j){
        float tj = 0.f;
#pragma unroll
        for (int i = 0; i < 4; ++i) tj += pl[i]*conf[i*4+j];
        s += tj*pr[j];
      }
      s = scrub0(s); s = fmaxf(s, 1e-35f);
      p2 = -logf(s);
    }
  }
  __shared__ float sh1[256], sh2[256];
  sh1[threadIdx.x] = p1; sh2[threadIdx.x] = p2;
  __syncthreads();
  for (int k = 128; k > 0; k >>= 1){
    if (threadIdx.x < k){
      sh1[threadIdx.x] += sh1[threadIdx.x + k];
      sh2[threadIdx.x] += sh2[threadIdx.x + k];
    }
    __syncthreads();
  }
  if (threadIdx.x == 0){
    part_l1[blockIdx.x] = sh1[0];
    part_l2[blockIdx.x] = sh2[0];
  }
}

// ---- loss final reduce (Kahan) -> out[0] ----
__global__ __launch_bounds__(256) void k_floss(const float* __restrict__ part_l1,
    const float* __restrict__ part_l2, float* __restrict__ out){
  const int tid = threadIdx.x;
  float a = 0.f, ca = 0.f, b = 0.f, cb = 0.f;
  for (int i = tid; i < NB_LOSS; i += 256){
    float y = part_l1[i] - ca; float t = a + y; ca = (t - a) - y; a = t;
    float y2 = part_l2[i] - cb; float t2 = b + y2; cb = (t2 - b) - y2; b = t2;
  }
  __shared__ float sh1[256], sh2[256];
  sh1[tid] = a; sh2[tid] = b;
  __syncthreads();
  for (int k = 128; k > 0; k >>= 1){
    if (tid < k){ sh1[tid] += sh1[tid + k]; sh2[tid] += sh2[tid + k]; }
    __syncthreads();
  }
  if (tid == 0)
    out[0] = sh1[0]/(float)N_EDGES + sh2[0]/(10.f*(float)N_CONFP);
}

extern "C" void kernel_launch(void* const* d_in, const int* in_sizes, int n_in,
                              void* d_out, int out_size, void* d_ws, size_t ws_size,
                              hipStream_t stream){
  const float* state0  = (const float*)d_in[0];
  const float* W1      = (const float*)d_in[1];
  const float* b1v     = (const float*)d_in[2];
  const float* W2      = (const float*)d_in[3];
  const float* b2v     = (const float*)d_in[4];
  const float* ln_g    = (const float*)d_in[5];
  const float* ln_b    = (const float*)d_in[6];
  const float* bn_g    = (const float*)d_in[7];
  const float* bn_b    = (const float*)d_in[8];
  const float* Wd      = (const float*)d_in[9];
  const float* bd      = (const float*)d_in[10];
  const float* rel     = (const float*)d_in[11];
  const float* confm   = (const float*)d_in[12];
  const float* degrees = (const float*)d_in[13];
  const int* idxL = (const int*)d_in[14];
  const int* idxR = (const int*)d_in[15];
  const int* iLp  = (const int*)d_in[16];
  const int* iRp  = (const int*)d_in[17];

  // workspace: total ~82.6 MB (R1 execution proved >= 84.3 MB available)
  char* ws = (char*)d_ws;
  float*  state     = (float*)(ws);                   // 20,480,000
  float*  PQ        = (float*)(ws + 20480000);        // 40,960,000
  float*  agg       = (float*)(ws + 61440000);        // 20,480,000
  int*    asg       = (int*)  (ws + 81920000);        //    480,000
  float*  red_part  = (float*)(ws + 82400000);        //    160,768
  float*  red       = (float*)(ws + 82560768);        //      1,024
  float*  part_l1   = (float*)(ws + 82561792);        //     14,068
  float*  part_l2   = (float*)(ws + 82575860);        //     14,068
  (void)ws_size;

  float* out     = (float*)d_out;
  float* out_phi = out + 2;
  float* out_ec  = out + 480002;
  float* out_asg = out + 1080002;

  k_zero_out<<<(OUT_TOTAL + 255)/256, 256, 0, stream>>>(out, OUT_TOTAL);

  for (int t = 0; t < T_ITERS; ++t){
    k_zero_agg<<<5000, 256, 0, stream>>>((float4*)agg);
    k_pq<<<N_VARS/16, 256, 0, stream>>>((t == 0) ? state0 : state, W1, PQ);
    k_edge<<<(2*N_EDGES)/16, 128, 0, stream>>>(PQ, W2, b1v, b2v, ln_g, ln_b, idxL, idxR, agg);
    k_stats<<<NB_STAT, 256, 0, stream>>>(agg, degrees, red_part);
    k_red<<<1, 256, 0, stream>>>(red_part, red);
    k_bn<<<N_VARS/4, 256, 0, stream>>>(agg, degrees, red, bn_g, bn_b, Wd, bd,
                                       state, asg, out_phi, out_asg, t);
  }
  k_conf<<<NB_CONF, 256, 0, stream>>>(asg, idxL, idxR, rel, out_ec);
  k_nconf<<<1, 256, 0, stream>>>(asg, idxL, idxR, rel, out);
  k_loss<<<NB_LOSS, 256, 0, stream>>>(out_phi, idxL, idxR, iLp, iRp, rel, confm, part_l1, part_l2);
  k_floss<<<1, 256, 0, stream>>>(part_l1, part_l2, out);
}

// Round 7
// 1394.366 us; speedup vs baseline: 1.2820x; 1.2820x over previous
//
#include <hip/hip_runtime.h>
#include <math.h>

#define N_VARS 40000
#define FEAT 128
#define N_EDGES 200000
#define N_CONFP 100000
#define T_ITERS 3
#define EPSF 1e-5f

#define NB_CONF 782              // ceil(200000/256)
#define NB_LOSS 3517             // ceil(900000/256)
#define NB_STAT 157              // ceil(40000/256)
#define OUT_TOTAL 1120003
#define NCONF_SLOT 1120002       // sequential carve: 1+1+480000+600000+40000

// integer-bit NaN/Inf scrub (immune to fast-math): NaN/Inf -> 0
__device__ __forceinline__ float scrub0(float x){
  unsigned u = __float_as_uint(x);
  return ((u & 0x7F800000u) == 0x7F800000u) ? 0.f : x;
}

// ---- zero entire float output buffer ----
__global__ __launch_bounds__(256) void k_zero_out(float* __restrict__ out, int n){
  int i = blockIdx.x*256 + threadIdx.x;
  if (i < n) out[i] = 0.f;
}
// ---- zero agg: 5000*256 float4 == N_VARS*FEAT floats exactly ----
__global__ __launch_bounds__(256) void k_zero_agg(float4* __restrict__ p){
  p[blockIdx.x*256 + threadIdx.x] = make_float4(0.f,0.f,0.f,0.f);
}

// ---- PQ = x @ [W1top | W1bot]  (N x 256), fp32 ----
__global__ __launch_bounds__(256) void k_pq(const float* __restrict__ x,
                                            const float* __restrict__ W1,
                                            float* __restrict__ PQ){
  __shared__ float sA[16][FEAT];
  const int tid = threadIdx.x;
  const int row0 = blockIdx.x * 16;
#pragma unroll
  for (int i = 0; i < 8; ++i){
    int idx = tid + i*256;
    sA[idx >> 7][idx & 127] = x[row0*FEAT + idx];
  }
  __syncthreads();
  const int half_sel = tid >> 7;   // 0: W1 rows 0..127 (P), 1: rows 128..255 (Q)
  const int col  = tid & 127;
  float acc[16];
#pragma unroll
  for (int r = 0; r < 16; ++r) acc[r] = 0.f;
  const float* Wb = W1 + (half_sel*FEAT)*FEAT + col;
  for (int kq = 0; kq < FEAT/4; ++kq){
    float w0 = Wb[(kq*4+0)*FEAT];
    float w1 = Wb[(kq*4+1)*FEAT];
    float w2 = Wb[(kq*4+2)*FEAT];
    float w3 = Wb[(kq*4+3)*FEAT];
#pragma unroll
    for (int r = 0; r < 16; ++r){
      const float4 v = *(const float4*)&sA[r][kq*4];
      acc[r] = fmaf(v.x, w0, acc[r]);
      acc[r] = fmaf(v.y, w1, acc[r]);
      acc[r] = fmaf(v.z, w2, acc[r]);
      acc[r] = fmaf(v.w, w3, acc[r]);
    }
  }
#pragma unroll
  for (int r = 0; r < 16; ++r)
    PQ[(row0 + r)*2*FEAT + tid] = acc[r];
}

// ---- edge kernel: 32 messages/block, 256 threads (4 waves) ----
// U = relu(P[b]+Q[a]+b1); Z = relu(U@W2 + b2); LN; atomic scatter to agg[a]
__global__ __launch_bounds__(256) void k_edge(const float* __restrict__ PQ,
    const float* __restrict__ W2, const float* __restrict__ b1v,
    const float* __restrict__ b2v, const float* __restrict__ ln_g, const float* __restrict__ ln_b,
    const int* __restrict__ idxL, const int* __restrict__ idxR,
    float* __restrict__ agg){
  __shared__ float sU[32][FEAT];
  __shared__ int sTa[32], sTb[32];
  const int tid = threadIdx.x;
  const int m0 = blockIdx.x * 32;
  if (tid < 32){
    int m = m0 + tid;
    int e = (m < N_EDGES) ? m : (m - N_EDGES);
    int l = idxL[e], r = idxR[e];
    sTa[tid] = (m < N_EDGES) ? l : r;   // scatter target + Q row
    sTb[tid] = (m < N_EDGES) ? r : l;   // P row
  }
  __syncthreads();
  const int col = tid & 127;
  const int grp = tid >> 7;             // rows grp*16 .. grp*16+15
  const float b1t = b1v[col];
#pragma unroll
  for (int r = 0; r < 16; ++r){
    int row = grp*16 + r;
    float u = PQ[sTb[row]*(2*FEAT) + col] + PQ[sTa[row]*(2*FEAT) + FEAT + col] + b1t;
    sU[row][col] = fmaxf(u, 0.f);
  }
  __syncthreads();
  float acc[16];
#pragma unroll
  for (int r = 0; r < 16; ++r) acc[r] = 0.f;
  const float* Wb = W2 + col;
  for (int kq = 0; kq < FEAT/4; ++kq){
    float w0 = Wb[(kq*4+0)*FEAT];
    float w1 = Wb[(kq*4+1)*FEAT];
    float w2 = Wb[(kq*4+2)*FEAT];
    float w3 = Wb[(kq*4+3)*FEAT];
#pragma unroll
    for (int r = 0; r < 16; ++r){
      const float4 v = *(const float4*)&sU[grp*16 + r][kq*4];
      acc[r] = fmaf(v.x, w0, acc[r]);
      acc[r] = fmaf(v.y, w1, acc[r]);
      acc[r] = fmaf(v.z, w2, acc[r]);
      acc[r] = fmaf(v.w, w3, acc[r]);
    }
  }
  const float b2t = b2v[col];
  __syncthreads();
#pragma unroll
  for (int r = 0; r < 16; ++r)
    sU[grp*16 + r][col] = fmaxf(acc[r] + b2t, 0.f);
  __syncthreads();
  // LN + scatter: 4 waves, wave wv handles rows wv*8 .. wv*8+7
  const int wv = tid >> 6, l = tid & 63;
  const float g0 = ln_g[l],  g1 = ln_g[l+64];
  const float be0 = ln_b[l], be1 = ln_b[l+64];
#pragma unroll
  for (int r8 = 0; r8 < 8; ++r8){
    int r = wv*8 + r8;
    float v0 = sU[r][l], v1 = sU[r][l+64];
    float s = v0 + v1, q = v0*v0 + v1*v1;
#pragma unroll
    for (int o = 32; o > 0; o >>= 1){ s += __shfl_xor(s, o); q += __shfl_xor(q, o); }
    float mu = s * (1.f/FEAT);
    float var = fmaxf(q * (1.f/FEAT) - mu*mu, 0.f);
    float rv = rsqrtf(var + EPSF);
    int a = sTa[r];
    float o0 = scrub0(g0*(v0-mu)*rv + be0);
    float o1 = scrub0(g1*(v1-mu)*rv + be1);
    atomicAdd(&agg[a*FEAT + l],      o0);
    atomicAdd(&agg[a*FEAT + l + 64], o1);
  }
}

// ---- BN stats: per-block fp32 partial sum/sumsq of rec = agg/deg ----
__global__ __launch_bounds__(256) void k_stats(const float* __restrict__ agg,
    const float* __restrict__ degrees, float* __restrict__ red_part){
  const int tid = threadIdx.x;
  const int j = tid & 127, half_sel = tid >> 7;
  const int n0 = blockIdx.x * 256;
  float s1 = 0.f, s2 = 0.f;
  for (int i = half_sel; i < 256; i += 2){
    int n = n0 + i;
    if (n < N_VARS){
      float v = agg[n*FEAT + j] / degrees[n];
      s1 += v;
      s2 += v*v;
    }
  }
  __shared__ float sh1[256], sh2[256];
  sh1[tid] = s1; sh2[tid] = s2;
  __syncthreads();
  if (half_sel == 0){
    red_part[blockIdx.x*256 + j]       = sh1[tid] + sh1[tid+128];
    red_part[blockIdx.x*256 + 128 + j] = sh2[tid] + sh2[tid+128];
  }
}

// ---- reduce red_part -> red[256] (Kahan, single block, deterministic) ----
__global__ __launch_bounds__(256) void k_red(const float* __restrict__ red_part,
                                             float* __restrict__ red){
  const int tid = threadIdx.x;
  float s = 0.f, c = 0.f;
  for (int b = 0; b < NB_STAT; ++b){
    float y = red_part[b*256 + tid] - c;
    float t = s + y;
    c = (t - s) - y;
    s = t;
  }
  red[tid] = s;
}

// ---- BN apply + logits + softmax + argmax; one wave per row ----
__global__ __launch_bounds__(256) void k_bn(const float* __restrict__ agg,
    const float* __restrict__ degrees, const float* __restrict__ red,
    const float* __restrict__ bn_g, const float* __restrict__ bn_b,
    const float* __restrict__ Wd, const float* __restrict__ bd,
    float* __restrict__ state, int* __restrict__ asg,
    float* __restrict__ out_phi, float* __restrict__ out_asg, int t){
  const int w = threadIdx.x >> 6, l = threadIdx.x & 63;
  const int n = blockIdx.x*4 + w;
  const float invN = 1.f / (float)N_VARS;
  float mu0 = red[l]*invN,     mu1 = red[l+64]*invN;
  float v0  = fmaxf(red[128+l]*invN    - mu0*mu0, 0.f);
  float v1  = fmaxf(red[128+l+64]*invN - mu1*mu1, 0.f);
  float rv0 = rsqrtf(v0 + EPSF);
  float rv1 = rsqrtf(v1 + EPSF);
  float dinv = 1.f / degrees[n];
  float r0 = agg[n*FEAT + l]    * dinv;
  float r1 = agg[n*FEAT + l+64] * dinv;
  float s0 = scrub0(bn_g[l]   *(r0 - mu0)*rv0 + bn_b[l]);
  float s1 = scrub0(bn_g[l+64]*(r1 - mu1)*rv1 + bn_b[l+64]);
  state[n*FEAT + l]    = s0;
  state[n*FEAT + l+64] = s1;
  float p[4];
#pragma unroll
  for (int d = 0; d < 4; ++d)
    p[d] = s0*Wd[l*4 + d] + s1*Wd[(l+64)*4 + d];
#pragma unroll
  for (int o = 32; o > 0; o >>= 1){
#pragma unroll
    for (int d = 0; d < 4; ++d) p[d] += __shfl_xor(p[d], o);
  }
  if (l == 0){
    float lg[4];
#pragma unroll
    for (int d = 0; d < 4; ++d) lg[d] = scrub0(p[d] + bd[d]);
    float mx = fmaxf(fmaxf(lg[0],lg[1]), fmaxf(lg[2],lg[3]));
    float ex[4]; float ssum = 0.f;
#pragma unroll
    for (int d = 0; d < 4; ++d){ ex[d] = expf(lg[d] - mx); ssum += ex[d]; }
    float inv = 1.f / ssum;
    int am = 0; float bv = -1.f;
#pragma unroll
    for (int d = 0; d < 4; ++d){
      float pv = scrub0(ex[d]*inv);
      out_phi[n*12 + t*4 + d] = pv;
      if (pv > bv){ bv = pv; am = d; }
    }
    asg[n*3 + t] = am;
    if (t == 2) out_asg[n] = (float)am;
  }
}

// ---- edge conflicts -> out_ec + per-block partial of t=2 column ----
__global__ __launch_bounds__(256) void k_conf(const int* __restrict__ asg,
    const int* __restrict__ idxL, const int* __restrict__ idxR,
    const float* __restrict__ relation, float* __restrict__ out_ec,
    float* __restrict__ part_conf){
  const int e = blockIdx.x*256 + threadIdx.x;
  float c2 = 0.f;
  if (e < N_EDGES){
    int l = idxL[e], r = idxR[e];
#pragma unroll
    for (int tt = 0; tt < 3; ++tt){
      int ai = asg[l*3+tt] & 3, bi = asg[r*3+tt] & 3;
      float c = scrub0(1.f - relation[ai*4 + bi]);
      out_ec[e*3 + tt] = c;
      if (tt == 2) c2 = c;
    }
  }
  __shared__ float sh[256];
  sh[threadIdx.x] = c2;
  __syncthreads();
  for (int k = 128; k > 0; k >>= 1){
    if (threadIdx.x < k) sh[threadIdx.x] += sh[threadIdx.x + k];
    __syncthreads();
  }
  if (threadIdx.x == 0) part_conf[blockIdx.x] = sh[0];
}

// ---- final conflict reduce -> out[1], out[NCONF_SLOT] ----
__global__ __launch_bounds__(256) void k_fconf(const float* __restrict__ part_conf,
                                               float* __restrict__ out){
  const int tid = threadIdx.x;
  float s = 0.f;
  for (int i = tid; i < NB_CONF; i += 256) s += part_conf[i];
  __shared__ float sh[256];
  sh[tid] = s;
  __syncthreads();
  for (int k = 128; k > 0; k >>= 1){
    if (tid < k) sh[tid] += sh[tid + k];
    __syncthreads();
  }
  if (tid == 0){
    float nc = sh[0];
    out[NCONF_SLOT] = nc;
    out[1] = nc / (float)N_EDGES;
  }
}

// ---- pair losses from fp32 phi (in d_out): per-block partials ----
__global__ __launch_bounds__(256) void k_loss(const float* __restrict__ phi,
    const int* __restrict__ iL, const int* __restrict__ iR,
    const int* __restrict__ iLp, const int* __restrict__ iRp,
    const float* __restrict__ rel, const float* __restrict__ conf,
    float* __restrict__ part_l1, float* __restrict__ part_l2){
  const int m = blockIdx.x*256 + threadIdx.x;
  float p1 = 0.f, p2 = 0.f;
  if (m < N_EDGES*3){
    int e = m/3, tt = m - e*3;
    const float* pl = phi + iL[e]*12 + tt*4;
    const float* pr = phi + iR[e]*12 + tt*4;
    float s = 0.f;
#pragma unroll
    for (int j = 0; j < 4; ++j){
      float tj = 0.f;
#pragma unroll
      for (int i = 0; i < 4; ++i) tj += pl[i]*rel[i*4+j];
      s += tj*pr[j];
    }
    s = scrub0(s); s = fmaxf(s, 1e-35f);
    p1 = -logf(s);
  } else {
    int m2 = m - N_EDGES*3;
    if (m2 < N_CONFP*3){
      int e = m2/3, tt = m2 - e*3;
      const float* pl = phi + iLp[e]*12 + tt*4;
      const float* pr = phi + iRp[e]*12 + tt*4;
      float s = 0.f;
#pragma unroll
      for (int j = 0; j < 4; ++j){
        float tj = 0.f;
#pragma unroll
        for (int i = 0; i < 4; ++i) tj += pl[i]*conf[i*4+j];
        s += tj*pr[j];
      }
      s = scrub0(s); s = fmaxf(s, 1e-35f);
      p2 = -logf(s);
    }
  }
  __shared__ float sh1[256], sh2[256];
  sh1[threadIdx.x] = p1; sh2[threadIdx.x] = p2;
  __syncthreads();
  for (int k = 128; k > 0; k >>= 1){
    if (threadIdx.x < k){
      sh1[threadIdx.x] += sh1[threadIdx.x + k];
      sh2[threadIdx.x] += sh2[threadIdx.x + k];
    }
    __syncthreads();
  }
  if (threadIdx.x == 0){
    part_l1[blockIdx.x] = sh1[0];
    part_l2[blockIdx.x] = sh2[0];
  }
}

// ---- loss final reduce (Kahan) -> out[0] ----
__global__ __launch_bounds__(256) void k_floss(const float* __restrict__ part_l1,
    const float* __restrict__ part_l2, float* __restrict__ out){
  const int tid = threadIdx.x;
  float a = 0.f, ca = 0.f, b = 0.f, cb = 0.f;
  for (int i = tid; i < NB_LOSS; i += 256){
    float y = part_l1[i] - ca; float t = a + y; ca = (t - a) - y; a = t;
    float y2 = part_l2[i] - cb; float t2 = b + y2; cb = (t2 - b) - y2; b = t2;
  }
  __shared__ float sh1[256], sh2[256];
  sh1[tid] = a; sh2[tid] = b;
  __syncthreads();
  for (int k = 128; k > 0; k >>= 1){
    if (tid < k){ sh1[tid] += sh1[tid + k]; sh2[tid] += sh2[tid + k]; }
    __syncthreads();
  }
  if (tid == 0)
    out[0] = sh1[0]/(float)N_EDGES + sh2[0]/(10.f*(float)N_CONFP);
}

extern "C" void kernel_launch(void* const* d_in, const int* in_sizes, int n_in,
                              void* d_out, int out_size, void* d_ws, size_t ws_size,
                              hipStream_t stream){
  const float* state0  = (const float*)d_in[0];
  const float* W1      = (const float*)d_in[1];
  const float* b1v     = (const float*)d_in[2];
  const float* W2      = (const float*)d_in[3];
  const float* b2v     = (const float*)d_in[4];
  const float* ln_g    = (const float*)d_in[5];
  const float* ln_b    = (const float*)d_in[6];
  const float* bn_g    = (const float*)d_in[7];
  const float* bn_b    = (const float*)d_in[8];
  const float* Wd      = (const float*)d_in[9];
  const float* bd      = (const float*)d_in[10];
  const float* rel     = (const float*)d_in[11];
  const float* confm   = (const float*)d_in[12];
  const float* degrees = (const float*)d_in[13];
  const int* idxL = (const int*)d_in[14];
  const int* idxR = (const int*)d_in[15];
  const int* iLp  = (const int*)d_in[16];
  const int* iRp  = (const int*)d_in[17];

  char* ws = (char*)d_ws;
  float*  state     = (float*)(ws);                   // 20,480,000
  float*  PQ        = (float*)(ws + 20480000);        // 40,960,000
  float*  agg       = (float*)(ws + 61440000);        // 20,480,000
  int*    asg       = (int*)  (ws + 81920000);        //    480,000
  float*  red_part  = (float*)(ws + 82400000);        //    160,768
  float*  red       = (float*)(ws + 82560768);        //      1,024
  float*  part_l1   = (float*)(ws + 82561792);        //     14,068
  float*  part_l2   = (float*)(ws + 82575860);        //     14,068
  float*  part_conf = (float*)(ws + 82589928);        //      3,128
  (void)ws_size;

  float* out     = (float*)d_out;
  float* out_phi = out + 2;
  float* out_ec  = out + 480002;
  float* out_asg = out + 1080002;

  k_zero_out<<<(OUT_TOTAL + 255)/256, 256, 0, stream>>>(out, OUT_TOTAL);

  for (int t = 0; t < T_ITERS; ++t){
    k_zero_agg<<<5000, 256, 0, stream>>>((float4*)agg);
    k_pq<<<N_VARS/16, 256, 0, stream>>>((t == 0) ? state0 : state, W1, PQ);
    k_edge<<<(2*N_EDGES)/32, 256, 0, stream>>>(PQ, W2, b1v, b2v, ln_g, ln_b, idxL, idxR, agg);
    k_stats<<<NB_STAT, 256, 0, stream>>>(agg, degrees, red_part);
    k_red<<<1, 256, 0, stream>>>(red_part, red);
    k_bn<<<N_VARS/4, 256, 0, stream>>>(agg, degrees, red, bn_g, bn_b, Wd, bd,
                                       state, asg, out_phi, out_asg, t);
  }
  k_conf<<<NB_CONF, 256, 0, stream>>>(asg, idxL, idxR, rel, out_ec, part_conf);
  k_fconf<<<1, 256, 0, stream>>>(part_conf, out);
  k_loss<<<NB_LOSS, 256, 0, stream>>>(out_phi, idxL, idxR, iLp, iRp, rel, confm, part_l1, part_l2);
  k_floss<<<1, 256, 0, stream>>>(part_l1, part_l2, out);
}

// Round 8
// 1041.915 us; speedup vs baseline: 1.7157x; 1.3383x over previous
//
#include <hip/hip_runtime.h>
#include <math.h>

#define N_VARS 40000
#define FEAT 128
#define N_EDGES 200000
#define N_CONFP 100000
#define T_ITERS 3
#define EPSF 1e-5f

#define NB_CONF 782              // ceil(200000/256)
#define NB_LOSS 3517             // ceil(900000/256)
#define NB_STAT 157              // ceil(40000/256)
#define OUT_TOTAL 1120003
#define NCONF_SLOT 1120002       // sequential carve: 1+1+480000+600000+40000

typedef short short8 __attribute__((ext_vector_type(8)));
typedef float floatx4 __attribute__((ext_vector_type(4)));

// integer-bit NaN/Inf scrub (immune to fast-math): NaN/Inf -> 0
__device__ __forceinline__ float scrub0(float x){
  unsigned u = __float_as_uint(x);
  return ((u & 0x7F800000u) == 0x7F800000u) ? 0.f : x;
}
// f32 -> bf16 bits, round-to-nearest-even
__device__ __forceinline__ unsigned short f2bf_rne(float x){
  unsigned u = __float_as_uint(x);
  u += 0x7FFFu + ((u >> 16) & 1u);
  return (unsigned short)(u >> 16);
}

// ---- zero entire float output buffer ----
__global__ __launch_bounds__(256) void k_zero_out(float* __restrict__ out, int n){
  int i = blockIdx.x*256 + threadIdx.x;
  if (i < n) out[i] = 0.f;
}
// ---- zero agg: 5000*256 float4 == N_VARS*FEAT floats exactly ----
__global__ __launch_bounds__(256) void k_zero_agg(float4* __restrict__ p){
  p[blockIdx.x*256 + threadIdx.x] = make_float4(0.f,0.f,0.f,0.f);
}

// ---- pack W2 (128x128 f32) into B-fragment-ordered bf16 ----
// layout: frag (ntg 0..7, ks 0..3, lane 0..63) -> 8 contiguous bf16:
//   W2pack[((ntg*4+ks)*64+lane)*8 + j] = bf16( W2[(ks*32+(lane>>4)*8+j)*128 + ntg*16+(lane&15)] )
__global__ __launch_bounds__(256) void k_prep(const float* __restrict__ W2,
                                              unsigned short* __restrict__ W2pack){
  int gid = blockIdx.x*256 + threadIdx.x;   // 0..2047
  int lane = gid & 63;
  int ks = (gid >> 6) & 3;
  int ntg = gid >> 8;
  int kbase = ks*32 + (lane >> 4)*8;
  int n = ntg*16 + (lane & 15);
#pragma unroll
  for (int j = 0; j < 8; ++j)
    W2pack[gid*8 + j] = f2bf_rne(W2[(kbase + j)*FEAT + n]);
}

// ---- PQ = x @ [W1top | W1bot]  (N x 256), fp32 ----
__global__ __launch_bounds__(256) void k_pq(const float* __restrict__ x,
                                            const float* __restrict__ W1,
                                            float* __restrict__ PQ){
  __shared__ float sA[16][FEAT];
  const int tid = threadIdx.x;
  const int row0 = blockIdx.x * 16;
#pragma unroll
  for (int i = 0; i < 8; ++i){
    int idx = tid + i*256;
    sA[idx >> 7][idx & 127] = x[row0*FEAT + idx];
  }
  __syncthreads();
  const int half_sel = tid >> 7;
  const int col  = tid & 127;
  float acc[16];
#pragma unroll
  for (int r = 0; r < 16; ++r) acc[r] = 0.f;
  const float* Wb = W1 + (half_sel*FEAT)*FEAT + col;
  for (int kq = 0; kq < FEAT/4; ++kq){
    float w0 = Wb[(kq*4+0)*FEAT];
    float w1 = Wb[(kq*4+1)*FEAT];
    float w2 = Wb[(kq*4+2)*FEAT];
    float w3 = Wb[(kq*4+3)*FEAT];
#pragma unroll
    for (int r = 0; r < 16; ++r){
      const float4 v = *(const float4*)&sA[r][kq*4];
      acc[r] = fmaf(v.x, w0, acc[r]);
      acc[r] = fmaf(v.y, w1, acc[r]);
      acc[r] = fmaf(v.z, w2, acc[r]);
      acc[r] = fmaf(v.w, w3, acc[r]);
    }
  }
#pragma unroll
  for (int r = 0; r < 16; ++r)
    PQ[(row0 + r)*2*FEAT + tid] = acc[r];
}

// ---- edge kernel: 32 messages/block, 256 threads, MFMA-bf16 U@W2 ----
#define U_STRIDE 136   // bf16 elems; 272 B rows (16B-aligned), breaks b128 bank aliasing
#define Z_STRIDE 132   // f32 elems; 528 B rows (16B-aligned)
__global__ __launch_bounds__(256) void k_edge(const float* __restrict__ PQ,
    const unsigned short* __restrict__ W2pack, const float* __restrict__ b1v,
    const float* __restrict__ b2v, const float* __restrict__ ln_g, const float* __restrict__ ln_b,
    const int* __restrict__ idxL, const int* __restrict__ idxR,
    float* __restrict__ agg){
  __shared__ unsigned short Ubf[32*U_STRIDE];
  __shared__ float sZ[32*Z_STRIDE];
  __shared__ int sTa[32], sTb[32];
  const int tid = threadIdx.x;
  const int m0 = blockIdx.x * 32;
  if (tid < 32){
    int m = m0 + tid;
    int e = (m < N_EDGES) ? m : (m - N_EDGES);
    int l = idxL[e], r = idxR[e];
    sTa[tid] = (m < N_EDGES) ? l : r;   // scatter target + Q row
    sTb[tid] = (m < N_EDGES) ? r : l;   // P row
  }
  __syncthreads();
  // stage U = relu(P[b] + Q[a] + b1) as bf16
  const int col = tid & 127;
  const int grp = tid >> 7;
  const float b1t = b1v[col];
#pragma unroll
  for (int r = 0; r < 16; ++r){
    int row = grp*16 + r;
    float u = PQ[sTb[row]*(2*FEAT) + col] + PQ[sTa[row]*(2*FEAT) + FEAT + col] + b1t;
    Ubf[row*U_STRIDE + col] = f2bf_rne(fmaxf(u, 0.f));
  }
  __syncthreads();
  // MFMA: wave w -> mt = w&1 (rows mt*16..+15), nhalf = w>>1 (cols nhalf*64..+63)
  const int w = tid >> 6, lane = tid & 63;
  const int mt = w & 1, nhalf = w >> 1;
  const int quad = lane >> 4, mcol = lane & 15;
  floatx4 acc0 = {0.f,0.f,0.f,0.f};
  floatx4 acc1 = {0.f,0.f,0.f,0.f};
  floatx4 acc2 = {0.f,0.f,0.f,0.f};
  floatx4 acc3 = {0.f,0.f,0.f,0.f};
#pragma unroll
  for (int ks = 0; ks < 4; ++ks){
    short8 a = *(const short8*)&Ubf[(mt*16 + mcol)*U_STRIDE + ks*32 + quad*8];
    const unsigned short* bp = W2pack + ((nhalf*4*256) + ks*64 + lane)*8;
    short8 bq0 = *(const short8*)(bp);
    short8 bq1 = *(const short8*)(bp + 2048);
    short8 bq2 = *(const short8*)(bp + 4096);
    short8 bq3 = *(const short8*)(bp + 6144);
    acc0 = __builtin_amdgcn_mfma_f32_16x16x32_bf16(a, bq0, acc0, 0, 0, 0);
    acc1 = __builtin_amdgcn_mfma_f32_16x16x32_bf16(a, bq1, acc1, 0, 0, 0);
    acc2 = __builtin_amdgcn_mfma_f32_16x16x32_bf16(a, bq2, acc2, 0, 0, 0);
    acc3 = __builtin_amdgcn_mfma_f32_16x16x32_bf16(a, bq3, acc3, 0, 0, 0);
  }
  // epilogue: Z = relu(acc + b2) into padded f32 LDS.  D: row=quad*4+reg, col=lane&15
#pragma unroll
  for (int nt = 0; nt < 4; ++nt){
    floatx4 a4 = (nt == 0) ? acc0 : (nt == 1) ? acc1 : (nt == 2) ? acc2 : acc3;
    int n = nhalf*64 + nt*16 + mcol;
    float bb = b2v[n];
#pragma unroll
    for (int reg = 0; reg < 4; ++reg){
      int row = mt*16 + quad*4 + reg;
      sZ[row*Z_STRIDE + n] = fmaxf(a4[reg] + bb, 0.f);
    }
  }
  __syncthreads();
  // LN + scatter: wave wv handles rows wv*8 .. wv*8+7
  const int wv = tid >> 6, l = tid & 63;
  const float g0 = ln_g[l],  g1 = ln_g[l+64];
  const float be0 = ln_b[l], be1 = ln_b[l+64];
#pragma unroll
  for (int r8 = 0; r8 < 8; ++r8){
    int r = wv*8 + r8;
    float v0 = sZ[r*Z_STRIDE + l], v1 = sZ[r*Z_STRIDE + l + 64];
    float s = v0 + v1, q = v0*v0 + v1*v1;
#pragma unroll
    for (int o = 32; o > 0; o >>= 1){ s += __shfl_xor(s, o); q += __shfl_xor(q, o); }
    float mu = s * (1.f/FEAT);
    float var = fmaxf(q * (1.f/FEAT) - mu*mu, 0.f);
    float rv = rsqrtf(var + EPSF);
    int a = sTa[r];
    float o0 = scrub0(g0*(v0-mu)*rv + be0);
    float o1 = scrub0(g1*(v1-mu)*rv + be1);
    atomicAdd(&agg[a*FEAT + l],      o0);
    atomicAdd(&agg[a*FEAT + l + 64], o1);
  }
}

// ---- BN stats: per-block fp32 partial sum/sumsq of rec = agg/deg ----
__global__ __launch_bounds__(256) void k_stats(const float* __restrict__ agg,
    const float* __restrict__ degrees, float* __restrict__ red_part){
  const int tid = threadIdx.x;
  const int j = tid & 127, half_sel = tid >> 7;
  const int n0 = blockIdx.x * 256;
  float s1 = 0.f, s2 = 0.f;
  for (int i = half_sel; i < 256; i += 2){
    int n = n0 + i;
    if (n < N_VARS){
      float v = agg[n*FEAT + j] / degrees[n];
      s1 += v;
      s2 += v*v;
    }
  }
  __shared__ float sh1[256], sh2[256];
  sh1[tid] = s1; sh2[tid] = s2;
  __syncthreads();
  if (half_sel == 0){
    red_part[blockIdx.x*256 + j]       = sh1[tid] + sh1[tid+128];
    red_part[blockIdx.x*256 + 128 + j] = sh2[tid] + sh2[tid+128];
  }
}

// ---- reduce red_part -> red[256] (Kahan, single block, deterministic) ----
__global__ __launch_bounds__(256) void k_red(const float* __restrict__ red_part,
                                             float* __restrict__ red){
  const int tid = threadIdx.x;
  float s = 0.f, c = 0.f;
  for (int b = 0; b < NB_STAT; ++b){
    float y = red_part[b*256 + tid] - c;
    float t = s + y;
    c = (t - s) - y;
    s = t;
  }
  red[tid] = s;
}

// ---- BN apply + logits + softmax + argmax; one wave per row ----
__global__ __launch_bounds__(256) void k_bn(const float* __restrict__ agg,
    const float* __restrict__ degrees, const float* __restrict__ red,
    const float* __restrict__ bn_g, const float* __restrict__ bn_b,
    const float* __restrict__ Wd, const float* __restrict__ bd,
    float* __restrict__ state, int* __restrict__ asg,
    float* __restrict__ out_phi, float* __restrict__ out_asg, int t){
  const int w = threadIdx.x >> 6, l = threadIdx.x & 63;
  const int n = blockIdx.x*4 + w;
  const float invN = 1.f / (float)N_VARS;
  float mu0 = red[l]*invN,     mu1 = red[l+64]*invN;
  float v0  = fmaxf(red[128+l]*invN    - mu0*mu0, 0.f);
  float v1  = fmaxf(red[128+l+64]*invN - mu1*mu1, 0.f);
  float rv0 = rsqrtf(v0 + EPSF);
  float rv1 = rsqrtf(v1 + EPSF);
  float dinv = 1.f / degrees[n];
  float r0 = agg[n*FEAT + l]    * dinv;
  float r1 = agg[n*FEAT + l+64] * dinv;
  float s0 = scrub0(bn_g[l]   *(r0 - mu0)*rv0 + bn_b[l]);
  float s1 = scrub0(bn_g[l+64]*(r1 - mu1)*rv1 + bn_b[l+64]);
  state[n*FEAT + l]    = s0;
  state[n*FEAT + l+64] = s1;
  float p[4];
#pragma unroll
  for (int d = 0; d < 4; ++d)
    p[d] = s0*Wd[l*4 + d] + s1*Wd[(l+64)*4 + d];
#pragma unroll
  for (int o = 32; o > 0; o >>= 1){
#pragma unroll
    for (int d = 0; d < 4; ++d) p[d] += __shfl_xor(p[d], o);
  }
  if (l == 0){
    float lg[4];
#pragma unroll
    for (int d = 0; d < 4; ++d) lg[d] = scrub0(p[d] + bd[d]);
    float mx = fmaxf(fmaxf(lg[0],lg[1]), fmaxf(lg[2],lg[3]));
    float ex[4]; float ssum = 0.f;
#pragma unroll
    for (int d = 0; d < 4; ++d){ ex[d] = expf(lg[d] - mx); ssum += ex[d]; }
    float inv = 1.f / ssum;
    int am = 0; float bv = -1.f;
#pragma unroll
    for (int d = 0; d < 4; ++d){
      float pv = scrub0(ex[d]*inv);
      out_phi[n*12 + t*4 + d] = pv;
      if (pv > bv){ bv = pv; am = d; }
    }
    asg[n*3 + t] = am;
    if (t == 2) out_asg[n] = (float)am;
  }
}

// ---- edge conflicts -> out_ec + per-block partial of t=2 column ----
__global__ __launch_bounds__(256) void k_conf(const int* __restrict__ asg,
    const int* __restrict__ idxL, const int* __restrict__ idxR,
    const float* __restrict__ relation, float* __restrict__ out_ec,
    float* __restrict__ part_conf){
  const int e = blockIdx.x*256 + threadIdx.x;
  float c2 = 0.f;
  if (e < N_EDGES){
    int l = idxL[e], r = idxR[e];
#pragma unroll
    for (int tt = 0; tt < 3; ++tt){
      int ai = asg[l*3+tt] & 3, bi = asg[r*3+tt] & 3;
      float c = scrub0(1.f - relation[ai*4 + bi]);
      out_ec[e*3 + tt] = c;
      if (tt == 2) c2 = c;
    }
  }
  __shared__ float sh[256];
  sh[threadIdx.x] = c2;
  __syncthreads();
  for (int k = 128; k > 0; k >>= 1){
    if (threadIdx.x < k) sh[threadIdx.x] += sh[threadIdx.x + k];
    __syncthreads();
  }
  if (threadIdx.x == 0) part_conf[blockIdx.x] = sh[0];
}

// ---- final conflict reduce -> out[1], out[NCONF_SLOT] ----
__global__ __launch_bounds__(256) void k_fconf(const float* __restrict__ part_conf,
                                               float* __restrict__ out){
  const int tid = threadIdx.x;
  float s = 0.f;
  for (int i = tid; i < NB_CONF; i += 256) s += part_conf[i];
  __shared__ float sh[256];
  sh[tid] = s;
  __syncthreads();
  for (int k = 128; k > 0; k >>= 1){
    if (tid < k) sh[tid] += sh[tid + k];
    __syncthreads();
  }
  if (tid == 0){
    float nc = sh[0];
    out[NCONF_SLOT] = nc;
    out[1] = nc / (float)N_EDGES;
  }
}

// ---- pair losses from fp32 phi (in d_out): per-block partials ----
__global__ __launch_bounds__(256) void k_loss(const float* __restrict__ phi,
    const int* __restrict__ iL, const int* __restrict__ iR,
    const int* __restrict__ iLp, const int* __restrict__ iRp,
    const float* __restrict__ rel, const float* __restrict__ conf,
    float* __restrict__ part_l1, float* __restrict__ part_l2){
  const int m = blockIdx.x*256 + threadIdx.x;
  float p1 = 0.f, p2 = 0.f;
  if (m < N_EDGES*3){
    int e = m/3, tt = m - e*3;
    const float* pl = phi + iL[e]*12 + tt*4;
    const float* pr = phi + iR[e]*12 + tt*4;
    float s = 0.f;
#pragma unroll
    for (int j = 0; j < 4; ++j){
      float tj = 0.f;
#pragma unroll
      for (int i = 0; i < 4; ++i) tj += pl[i]*rel[i*4+j];
      s += tj*pr[j];
    }
    s = scrub0(s); s = fmaxf(s, 1e-35f);
    p1 = -logf(s);
  } else {
    int m2 = m - N_EDGES*3;
    if (m2 < N_CONFP*3){
      int e = m2/3, tt = m2 - e*3;
      const float* pl = phi + iLp[e]*12 + tt*4;
      const float* pr = phi + iRp[e]*12 + tt*4;
      float s = 0.f;
#pragma unroll
      for (int j = 0; j < 4; ++j){
        float tj = 0.f;
#pragma unroll
        for (int i = 0; i < 4; ++i) tj += pl[i]*conf[i*4+j];
        s += tj*pr[j];
      }
      s = scrub0(s); s = fmaxf(s, 1e-35f);
      p2 = -logf(s);
    }
  }
  __shared__ float sh1[256], sh2[256];
  sh1[threadIdx.x] = p1; sh2[threadIdx.x] = p2;
  __syncthreads();
  for (int k = 128; k > 0; k >>= 1){
    if (threadIdx.x < k){
      sh1[threadIdx.x] += sh1[threadIdx.x + k];
      sh2[threadIdx.x] += sh2[threadIdx.x + k];
    }
    __syncthreads();
  }
  if (threadIdx.x == 0){
    part_l1[blockIdx.x] = sh1[0];
    part_l2[blockIdx.x] = sh2[0];
  }
}

// ---- loss final reduce (Kahan) -> out[0] ----
__global__ __launch_bounds__(256) void k_floss(const float* __restrict__ part_l1,
    const float* __restrict__ part_l2, float* __restrict__ out){
  const int tid = threadIdx.x;
  float a = 0.f, ca = 0.f, b = 0.f, cb = 0.f;
  for (int i = tid; i < NB_LOSS; i += 256){
    float y = part_l1[i] - ca; float t = a + y; ca = (t - a) - y; a = t;
    float y2 = part_l2[i] - cb; float t2 = b + y2; cb = (t2 - b) - y2; b = t2;
  }
  __shared__ float sh1[256], sh2[256];
  sh1[tid] = a; sh2[tid] = b;
  __syncthreads();
  for (int k = 128; k > 0; k >>= 1){
    if (tid < k){ sh1[tid] += sh1[tid + k]; sh2[tid] += sh2[tid + k]; }
    __syncthreads();
  }
  if (tid == 0)
    out[0] = sh1[0]/(float)N_EDGES + sh2[0]/(10.f*(float)N_CONFP);
}

extern "C" void kernel_launch(void* const* d_in, const int* in_sizes, int n_in,
                              void* d_out, int out_size, void* d_ws, size_t ws_size,
                              hipStream_t stream){
  const float* state0  = (const float*)d_in[0];
  const float* W1      = (const float*)d_in[1];
  const float* b1v     = (const float*)d_in[2];
  const float* W2      = (const float*)d_in[3];
  const float* b2v     = (const float*)d_in[4];
  const float* ln_g    = (const float*)d_in[5];
  const float* ln_b    = (const float*)d_in[6];
  const float* bn_g    = (const float*)d_in[7];
  const float* bn_b    = (const float*)d_in[8];
  const float* Wd      = (const float*)d_in[9];
  const float* bd      = (const float*)d_in[10];
  const float* rel     = (const float*)d_in[11];
  const float* confm   = (const float*)d_in[12];
  const float* degrees = (const float*)d_in[13];
  const int* idxL = (const int*)d_in[14];
  const int* idxR = (const int*)d_in[15];
  const int* iLp  = (const int*)d_in[16];
  const int* iRp  = (const int*)d_in[17];

  char* ws = (char*)d_ws;
  float*  state     = (float*)(ws);                   // 20,480,000
  float*  PQ        = (float*)(ws + 20480000);        // 40,960,000
  float*  agg       = (float*)(ws + 61440000);        // 20,480,000
  int*    asg       = (int*)  (ws + 81920000);        //    480,000
  float*  red_part  = (float*)(ws + 82400000);        //    160,768
  float*  red       = (float*)(ws + 82560768);        //      1,024
  float*  part_l1   = (float*)(ws + 82561792);        //     14,068
  float*  part_l2   = (float*)(ws + 82575860);        //     14,068
  float*  part_conf = (float*)(ws + 82589928);        //      3,128
  unsigned short* W2pack = (unsigned short*)(ws + 82593056); // 32,768
  (void)ws_size;

  float* out     = (float*)d_out;
  float* out_phi = out + 2;
  float* out_ec  = out + 480002;
  float* out_asg = out + 1080002;

  k_zero_out<<<(OUT_TOTAL + 255)/256, 256, 0, stream>>>(out, OUT_TOTAL);
  k_prep<<<8, 256, 0, stream>>>(W2, W2pack);

  for (int t = 0; t < T_ITERS; ++t){
    k_zero_agg<<<5000, 256, 0, stream>>>((float4*)agg);
    k_pq<<<N_VARS/16, 256, 0, stream>>>((t == 0) ? state0 : state, W1, PQ);
    k_edge<<<(2*N_EDGES)/32, 256, 0, stream>>>(PQ, W2pack, b1v, b2v, ln_g, ln_b, idxL, idxR, agg);
    k_stats<<<NB_STAT, 256, 0, stream>>>(agg, degrees, red_part);
    k_red<<<1, 256, 0, stream>>>(red_part, red);
    k_bn<<<N_VARS/4, 256, 0, stream>>>(agg, degrees, red, bn_g, bn_b, Wd, bd,
                                       state, asg, out_phi, out_asg, t);
  }
  k_conf<<<NB_CONF, 256, 0, stream>>>(asg, idxL, idxR, rel, out_ec, part_conf);
  k_fconf<<<1, 256, 0, stream>>>(part_conf, out);
  k_loss<<<NB_LOSS, 256, 0, stream>>>(out_phi, idxL, idxR, iLp, iRp, rel, confm, part_l1, part_l2);
  k_floss<<<1, 256, 0, stream>>>(part_l1, part_l2, out);
}

// Round 9
// 936.623 us; speedup vs baseline: 1.9086x; 1.1124x over previous
//
#include <hip/hip_runtime.h>
#include <math.h>

#define N_VARS 40000
#define FEAT 128
#define N_EDGES 200000
#define N_CONFP 100000
#define T_ITERS 3
#define EPSF 1e-5f

#define NB_CONF 782              // ceil(200000/256)
#define NB_LOSS 3517             // ceil(900000/256)
#define NB_STAT 157              // ceil(40000/256)
#define OUT_TOTAL 1120003
#define NCONF_SLOT 1120002       // sequential carve: 1+1+480000+600000+40000

typedef short short8 __attribute__((ext_vector_type(8)));
typedef float floatx4 __attribute__((ext_vector_type(4)));
typedef unsigned short ushort4v __attribute__((ext_vector_type(4)));

// integer-bit NaN/Inf scrub (immune to fast-math): NaN/Inf -> 0
__device__ __forceinline__ float scrub0(float x){
  unsigned u = __float_as_uint(x);
  return ((u & 0x7F800000u) == 0x7F800000u) ? 0.f : x;
}
// f32 -> bf16 bits, round-to-nearest-even
__device__ __forceinline__ unsigned short f2bf_rne(float x){
  unsigned u = __float_as_uint(x);
  u += 0x7FFFu + ((u >> 16) & 1u);
  return (unsigned short)(u >> 16);
}

// ---- zero entire float output buffer ----
__global__ __launch_bounds__(256) void k_zero_out(float* __restrict__ out, int n){
  int i = blockIdx.x*256 + threadIdx.x;
  if (i < n) out[i] = 0.f;
}
// ---- zero agg: 5000*256 float4 == N_VARS*FEAT floats exactly ----
__global__ __launch_bounds__(256) void k_zero_agg(float4* __restrict__ p){
  p[blockIdx.x*256 + threadIdx.x] = make_float4(0.f,0.f,0.f,0.f);
}

// ---- pack W2 (128x128 f32) into B-fragment-ordered bf16 (8 ntiles) ----
__global__ __launch_bounds__(256) void k_prep(const float* __restrict__ W2,
                                              unsigned short* __restrict__ W2pack){
  int gid = blockIdx.x*256 + threadIdx.x;   // 0..2047
  int lane = gid & 63;
  int ks = (gid >> 6) & 3;
  int ntg = gid >> 8;
  int kbase = ks*32 + (lane >> 4)*8;
  int n = ntg*16 + (lane & 15);
#pragma unroll
  for (int j = 0; j < 8; ++j)
    W2pack[gid*8 + j] = f2bf_rne(W2[(kbase + j)*FEAT + n]);
}

// ---- pack W1 (256x128 f32) into combined 128x256 B-fragment bf16 (16 ntiles) ----
// B[k][n] = n<128 ? W1[k][n] : W1[128+k][n-128]   (P | Q columns)
__global__ __launch_bounds__(256) void k_prep_w1(const float* __restrict__ W1,
                                                 unsigned short* __restrict__ W1pack){
  int gid = blockIdx.x*256 + threadIdx.x;   // 0..4095
  int lane = gid & 63;
  int ks = (gid >> 6) & 3;
  int ntg = gid >> 8;                        // 0..15
  int kbase = ks*32 + (lane >> 4)*8;
  int n = ntg*16 + (lane & 15);
#pragma unroll
  for (int j = 0; j < 8; ++j){
    int k = kbase + j;
    float v = (n < 128) ? W1[k*FEAT + n] : W1[(128 + k)*FEAT + (n - 128)];
    W1pack[gid*8 + j] = f2bf_rne(v);
  }
}

// ---- PQ = x @ [W1top | W1bot]  (N x 256) via MFMA bf16; 32 rows/block ----
#define X_STRIDE 136
__global__ __launch_bounds__(256) void k_pq(const float* __restrict__ x,
                                            const unsigned short* __restrict__ W1pack,
                                            float* __restrict__ PQ){
  __shared__ __align__(16) unsigned short Xbf[32*X_STRIDE];
  const int tid = threadIdx.x;
  const int row0 = blockIdx.x * 32;
  const int c4 = (tid & 31)*4, g8 = tid >> 5;
#pragma unroll
  for (int r = 0; r < 4; ++r){
    int row = g8*4 + r;
    const float4 v = *(const float4*)&x[(row0 + row)*FEAT + c4];
    ushort4v u;
    u.x = f2bf_rne(v.x); u.y = f2bf_rne(v.y);
    u.z = f2bf_rne(v.z); u.w = f2bf_rne(v.w);
    *(ushort4v*)&Xbf[row*X_STRIDE + c4] = u;
  }
  __syncthreads();
  const int w = tid >> 6, lane = tid & 63;
  const int quad = lane >> 4, mcol = lane & 15;
#pragma unroll
  for (int mt = 0; mt < 2; ++mt){
    floatx4 a0 = {0.f,0.f,0.f,0.f};
    floatx4 a1 = {0.f,0.f,0.f,0.f};
    floatx4 a2 = {0.f,0.f,0.f,0.f};
    floatx4 a3 = {0.f,0.f,0.f,0.f};
#pragma unroll
    for (int ks = 0; ks < 4; ++ks){
      short8 a = *(const short8*)&Xbf[(mt*16 + mcol)*X_STRIDE + ks*32 + quad*8];
      const unsigned short* bp = W1pack + ((w*16 + ks)*64 + lane)*8;
      short8 b0 = *(const short8*)(bp);
      short8 b1 = *(const short8*)(bp + 2048);
      short8 b2 = *(const short8*)(bp + 4096);
      short8 b3 = *(const short8*)(bp + 6144);
      a0 = __builtin_amdgcn_mfma_f32_16x16x32_bf16(a, b0, a0, 0, 0, 0);
      a1 = __builtin_amdgcn_mfma_f32_16x16x32_bf16(a, b1, a1, 0, 0, 0);
      a2 = __builtin_amdgcn_mfma_f32_16x16x32_bf16(a, b2, a2, 0, 0, 0);
      a3 = __builtin_amdgcn_mfma_f32_16x16x32_bf16(a, b3, a3, 0, 0, 0);
    }
#pragma unroll
    for (int nt = 0; nt < 4; ++nt){
      floatx4 acc = (nt == 0) ? a0 : (nt == 1) ? a1 : (nt == 2) ? a2 : a3;
      int n = w*64 + nt*16 + mcol;
#pragma unroll
      for (int reg = 0; reg < 4; ++reg)
        PQ[(row0 + mt*16 + quad*4 + reg)*(2*FEAT) + n] = acc[reg];
    }
  }
}

// ---- edge kernel: 32 messages/block, MFMA-bf16 U@W2, overlaid LDS ----
#define U_STRIDE 136   // bf16 elems
#define Z_STRIDE 132   // f32 elems
__global__ __launch_bounds__(256) void k_edge(const float* __restrict__ PQ,
    const unsigned short* __restrict__ W2pack, const float* __restrict__ b1v,
    const float* __restrict__ b2v, const float* __restrict__ ln_g, const float* __restrict__ ln_b,
    const int* __restrict__ idxL, const int* __restrict__ idxR,
    float* __restrict__ agg){
  __shared__ __align__(16) unsigned char smem[32*Z_STRIDE*4];  // 16896 B union
  unsigned short* Ubf = (unsigned short*)smem;                  // phase 1: 32*136 bf16
  float* sZ = (float*)smem;                                     // phase 2: 32*132 f32
  __shared__ int sTa[32], sTb[32];
  const int tid = threadIdx.x;
  const int m0 = blockIdx.x * 32;
  if (tid < 32){
    int m = m0 + tid;
    int e = (m < N_EDGES) ? m : (m - N_EDGES);
    int l = idxL[e], r = idxR[e];
    sTa[tid] = (m < N_EDGES) ? l : r;   // scatter target + Q row
    sTb[tid] = (m < N_EDGES) ? r : l;   // P row
  }
  __syncthreads();
  // stage U = relu(P[b] + Q[a] + b1) as bf16, float4 gather
  const int c4 = (tid & 31)*4, g8 = tid >> 5;
  const float4 bb1 = *(const float4*)&b1v[c4];
#pragma unroll
  for (int r = 0; r < 4; ++r){
    int row = g8*4 + r;
    const float4 p = *(const float4*)&PQ[sTb[row]*(2*FEAT) + c4];
    const float4 q = *(const float4*)&PQ[sTa[row]*(2*FEAT) + FEAT + c4];
    ushort4v u;
    u.x = f2bf_rne(fmaxf(p.x + q.x + bb1.x, 0.f));
    u.y = f2bf_rne(fmaxf(p.y + q.y + bb1.y, 0.f));
    u.z = f2bf_rne(fmaxf(p.z + q.z + bb1.z, 0.f));
    u.w = f2bf_rne(fmaxf(p.w + q.w + bb1.w, 0.f));
    *(ushort4v*)&Ubf[row*U_STRIDE + c4] = u;
  }
  __syncthreads();
  // MFMA: wave w -> mt = w&1 (rows), nhalf = w>>1 (cols nhalf*64..+63)
  const int w = tid >> 6, lane = tid & 63;
  const int mt = w & 1, nhalf = w >> 1;
  const int quad = lane >> 4, mcol = lane & 15;
  floatx4 acc0 = {0.f,0.f,0.f,0.f};
  floatx4 acc1 = {0.f,0.f,0.f,0.f};
  floatx4 acc2 = {0.f,0.f,0.f,0.f};
  floatx4 acc3 = {0.f,0.f,0.f,0.f};
#pragma unroll
  for (int ks = 0; ks < 4; ++ks){
    short8 a = *(const short8*)&Ubf[(mt*16 + mcol)*U_STRIDE + ks*32 + quad*8];
    const unsigned short* bp = W2pack + ((nhalf*4*256) + ks*64 + lane)*8;
    short8 bq0 = *(const short8*)(bp);
    short8 bq1 = *(const short8*)(bp + 2048);
    short8 bq2 = *(const short8*)(bp + 4096);
    short8 bq3 = *(const short8*)(bp + 6144);
    acc0 = __builtin_amdgcn_mfma_f32_16x16x32_bf16(a, bq0, acc0, 0, 0, 0);
    acc1 = __builtin_amdgcn_mfma_f32_16x16x32_bf16(a, bq1, acc1, 0, 0, 0);
    acc2 = __builtin_amdgcn_mfma_f32_16x16x32_bf16(a, bq2, acc2, 0, 0, 0);
    acc3 = __builtin_amdgcn_mfma_f32_16x16x32_bf16(a, bq3, acc3, 0, 0, 0);
  }
  __syncthreads();   // all Ubf reads complete before sZ overlays it
  // epilogue: Z = relu(acc + b2). D: row=quad*4+reg, col=lane&15
#pragma unroll
  for (int nt = 0; nt < 4; ++nt){
    floatx4 a4 = (nt == 0) ? acc0 : (nt == 1) ? acc1 : (nt == 2) ? acc2 : acc3;
    int n = nhalf*64 + nt*16 + mcol;
    float bb = b2v[n];
#pragma unroll
    for (int reg = 0; reg < 4; ++reg){
      int row = mt*16 + quad*4 + reg;
      sZ[row*Z_STRIDE + n] = fmaxf(a4[reg] + bb, 0.f);
    }
  }
  __syncthreads();
  // LN + scatter: wave wv handles rows wv*8 .. wv*8+7
  const int wv = tid >> 6, l = tid & 63;
  const float g0 = ln_g[l],  g1 = ln_g[l+64];
  const float be0 = ln_b[l], be1 = ln_b[l+64];
#pragma unroll
  for (int r8 = 0; r8 < 8; ++r8){
    int r = wv*8 + r8;
    float v0 = sZ[r*Z_STRIDE + l], v1 = sZ[r*Z_STRIDE + l + 64];
    float s = v0 + v1, q = v0*v0 + v1*v1;
#pragma unroll
    for (int o = 32; o > 0; o >>= 1){ s += __shfl_xor(s, o); q += __shfl_xor(q, o); }
    float mu = s * (1.f/FEAT);
    float var = fmaxf(q * (1.f/FEAT) - mu*mu, 0.f);
    float rv = rsqrtf(var + EPSF);
    int a = sTa[r];
    float o0 = scrub0(g0*(v0-mu)*rv + be0);
    float o1 = scrub0(g1*(v1-mu)*rv + be1);
    atomicAdd(&agg[a*FEAT + l],      o0);
    atomicAdd(&agg[a*FEAT + l + 64], o1);
  }
}

// ---- BN stats: per-block fp32 partial sum/sumsq of rec = agg/deg ----
__global__ __launch_bounds__(256) void k_stats(const float* __restrict__ agg,
    const float* __restrict__ degrees, float* __restrict__ red_part){
  const int tid = threadIdx.x;
  const int j = tid & 127, half_sel = tid >> 7;
  const int n0 = blockIdx.x * 256;
  float s1 = 0.f, s2 = 0.f;
  for (int i = half_sel; i < 256; i += 2){
    int n = n0 + i;
    if (n < N_VARS){
      float v = agg[n*FEAT + j] / degrees[n];
      s1 += v;
      s2 += v*v;
    }
  }
  __shared__ float sh1[256], sh2[256];
  sh1[tid] = s1; sh2[tid] = s2;
  __syncthreads();
  if (half_sel == 0){
    red_part[blockIdx.x*256 + j]       = sh1[tid] + sh1[tid+128];
    red_part[blockIdx.x*256 + 128 + j] = sh2[tid] + sh2[tid+128];
  }
}

// ---- reduce red_part -> red[256] (Kahan, single block, deterministic) ----
__global__ __launch_bounds__(256) void k_red(const float* __restrict__ red_part,
                                             float* __restrict__ red){
  const int tid = threadIdx.x;
  float s = 0.f, c = 0.f;
  for (int b = 0; b < NB_STAT; ++b){
    float y = red_part[b*256 + tid] - c;
    float t = s + y;
    c = (t - s) - y;
    s = t;
  }
  red[tid] = s;
}

// ---- BN apply + logits + softmax + argmax; one wave per row ----
__global__ __launch_bounds__(256) void k_bn(const float* __restrict__ agg,
    const float* __restrict__ degrees, const float* __restrict__ red,
    const float* __restrict__ bn_g, const float* __restrict__ bn_b,
    const float* __restrict__ Wd, const float* __restrict__ bd,
    float* __restrict__ state, int* __restrict__ asg,
    float* __restrict__ out_phi, float* __restrict__ out_asg, int t){
  const int w = threadIdx.x >> 6, l = threadIdx.x & 63;
  const int n = blockIdx.x*4 + w;
  const float invN = 1.f / (float)N_VARS;
  float mu0 = red[l]*invN,     mu1 = red[l+64]*invN;
  float v0  = fmaxf(red[128+l]*invN    - mu0*mu0, 0.f);
  float v1  = fmaxf(red[128+l+64]*invN - mu1*mu1, 0.f);
  float rv0 = rsqrtf(v0 + EPSF);
  float rv1 = rsqrtf(v1 + EPSF);
  float dinv = 1.f / degrees[n];
  float r0 = agg[n*FEAT + l]    * dinv;
  float r1 = agg[n*FEAT + l+64] * dinv;
  float s0 = scrub0(bn_g[l]   *(r0 - mu0)*rv0 + bn_b[l]);
  float s1 = scrub0(bn_g[l+64]*(r1 - mu1)*rv1 + bn_b[l+64]);
  state[n*FEAT + l]    = s0;
  state[n*FEAT + l+64] = s1;
  float p[4];
#pragma unroll
  for (int d = 0; d < 4; ++d)
    p[d] = s0*Wd[l*4 + d] + s1*Wd[(l+64)*4 + d];
#pragma unroll
  for (int o = 32; o > 0; o >>= 1){
#pragma unroll
    for (int d = 0; d < 4; ++d) p[d] += __shfl_xor(p[d], o);
  }
  if (l == 0){
    float lg[4];
#pragma unroll
    for (int d = 0; d < 4; ++d) lg[d] = scrub0(p[d] + bd[d]);
    float mx = fmaxf(fmaxf(lg[0],lg[1]), fmaxf(lg[2],lg[3]));
    float ex[4]; float ssum = 0.f;
#pragma unroll
    for (int d = 0; d < 4; ++d){ ex[d] = expf(lg[d] - mx); ssum += ex[d]; }
    float inv = 1.f / ssum;
    int am = 0; float bv = -1.f;
#pragma unroll
    for (int d = 0; d < 4; ++d){
      float pv = scrub0(ex[d]*inv);
      out_phi[n*12 + t*4 + d] = pv;
      if (pv > bv){ bv = pv; am = d; }
    }
    asg[n*3 + t] = am;
    if (t == 2) out_asg[n] = (float)am;
  }
}

// ---- edge conflicts -> out_ec + per-block partial of t=2 column ----
__global__ __launch_bounds__(256) void k_conf(const int* __restrict__ asg,
    const int* __restrict__ idxL, const int* __restrict__ idxR,
    const float* __restrict__ relation, float* __restrict__ out_ec,
    float* __restrict__ part_conf){
  const int e = blockIdx.x*256 + threadIdx.x;
  float c2 = 0.f;
  if (e < N_EDGES){
    int l = idxL[e], r = idxR[e];
#pragma unroll
    for (int tt = 0; tt < 3; ++tt){
      int ai = asg[l*3+tt] & 3, bi = asg[r*3+tt] & 3;
      float c = scrub0(1.f - relation[ai*4 + bi]);
      out_ec[e*3 + tt] = c;
      if (tt == 2) c2 = c;
    }
  }
  __shared__ float sh[256];
  sh[threadIdx.x] = c2;
  __syncthreads();
  for (int k = 128; k > 0; k >>= 1){
    if (threadIdx.x < k) sh[threadIdx.x] += sh[threadIdx.x + k];
    __syncthreads();
  }
  if (threadIdx.x == 0) part_conf[blockIdx.x] = sh[0];
}

// ---- final conflict reduce -> out[1], out[NCONF_SLOT] ----
__global__ __launch_bounds__(256) void k_fconf(const float* __restrict__ part_conf,
                                               float* __restrict__ out){
  const int tid = threadIdx.x;
  float s = 0.f;
  for (int i = tid; i < NB_CONF; i += 256) s += part_conf[i];
  __shared__ float sh[256];
  sh[tid] = s;
  __syncthreads();
  for (int k = 128; k > 0; k >>= 1){
    if (tid < k) sh[tid] += sh[tid + k];
    __syncthreads();
  }
  if (tid == 0){
    float nc = sh[0];
    out[NCONF_SLOT] = nc;
    out[1] = nc / (float)N_EDGES;
  }
}

// ---- pair losses from fp32 phi (in d_out): per-block partials ----
__global__ __launch_bounds__(256) void k_loss(const float* __restrict__ phi,
    const int* __restrict__ iL, const int* __restrict__ iR,
    const int* __restrict__ iLp, const int* __restrict__ iRp,
    const float* __restrict__ rel, const float* __restrict__ conf,
    float* __restrict__ part_l1, float* __restrict__ part_l2){
  const int m = blockIdx.x*256 + threadIdx.x;
  float p1 = 0.f, p2 = 0.f;
  if (m < N_EDGES*3){
    int e = m/3, tt = m - e*3;
    const float* pl = phi + iL[e]*12 + tt*4;
    const float* pr = phi + iR[e]*12 + tt*4;
    float s = 0.f;
#pragma unroll
    for (int j = 0; j < 4; ++j){
      float tj = 0.f;
#pragma unroll
      for (int i = 0; i < 4; ++i) tj += pl[i]*rel[i*4+j];
      s += tj*pr[j];
    }
    s = scrub0(s); s = fmaxf(s, 1e-35f);
    p1 = -logf(s);
  } else {
    int m2 = m - N_EDGES*3;
    if (m2 < N_CONFP*3){
      int e = m2/3, tt = m2 - e*3;
      const float* pl = phi + iLp[e]*12 + tt*4;
      const float* pr = phi + iRp[e]*12 + tt*4;
      float s = 0.f;
#pragma unroll
      for (int j = 0; j < 4; ++j){
        float tj = 0.f;
#pragma unroll
        for (int i = 0; i < 4; ++i) tj += pl[i]*conf[i*4+j];
        s += tj*pr[j];
      }
      s = scrub0(s); s = fmaxf(s, 1e-35f);
      p2 = -logf(s);
    }
  }
  __shared__ float sh1[256], sh2[256];
  sh1[threadIdx.x] = p1; sh2[threadIdx.x] = p2;
  __syncthreads();
  for (int k = 128; k > 0; k >>= 1){
    if (threadIdx.x < k){
      sh1[threadIdx.x] += sh1[threadIdx.x + k];
      sh2[threadIdx.x] += sh2[threadIdx.x + k];
    }
    __syncthreads();
  }
  if (threadIdx.x == 0){
    part_l1[blockIdx.x] = sh1[0];
    part_l2[blockIdx.x] = sh2[0];
  }
}

// ---- loss final reduce (Kahan) -> out[0] ----
__global__ __launch_bounds__(256) void k_floss(const float* __restrict__ part_l1,
    const float* __restrict__ part_l2, float* __restrict__ out){
  const int tid = threadIdx.x;
  float a = 0.f, ca = 0.f, b = 0.f, cb = 0.f;
  for (int i = tid; i < NB_LOSS; i += 256){
    float y = part_l1[i] - ca; float t = a + y; ca = (t - a) - y; a = t;
    float y2 = part_l2[i] - cb; float t2 = b + y2; cb = (t2 - b) - y2; b = t2;
  }
  __shared__ float sh1[256], sh2[256];
  sh1[tid] = a; sh2[tid] = b;
  __syncthreads();
  for (int k = 128; k > 0; k >>= 1){
    if (tid < k){ sh1[tid] += sh1[tid + k]; sh2[tid] += sh2[tid + k]; }
    __syncthreads();
  }
  if (tid == 0)
    out[0] = sh1[0]/(float)N_EDGES + sh2[0]/(10.f*(float)N_CONFP);
}

extern "C" void kernel_launch(void* const* d_in, const int* in_sizes, int n_in,
                              void* d_out, int out_size, void* d_ws, size_t ws_size,
                              hipStream_t stream){
  const float* state0  = (const float*)d_in[0];
  const float* W1      = (const float*)d_in[1];
  const float* b1v     = (const float*)d_in[2];
  const float* W2      = (const float*)d_in[3];
  const float* b2v     = (const float*)d_in[4];
  const float* ln_g    = (const float*)d_in[5];
  const float* ln_b    = (const float*)d_in[6];
  const float* bn_g    = (const float*)d_in[7];
  const float* bn_b    = (const float*)d_in[8];
  const float* Wd      = (const float*)d_in[9];
  const float* bd      = (const float*)d_in[10];
  const float* rel     = (const float*)d_in[11];
  const float* confm   = (const float*)d_in[12];
  const float* degrees = (const float*)d_in[13];
  const int* idxL = (const int*)d_in[14];
  const int* idxR = (const int*)d_in[15];
  const int* iLp  = (const int*)d_in[16];
  const int* iRp  = (const int*)d_in[17];

  char* ws = (char*)d_ws;
  float*  state     = (float*)(ws);                   // 20,480,000
  float*  PQ        = (float*)(ws + 20480000);        // 40,960,000
  float*  agg       = (float*)(ws + 61440000);        // 20,480,000
  int*    asg       = (int*)  (ws + 81920000);        //    480,000
  float*  red_part  = (float*)(ws + 82400000);        //    160,768
  float*  red       = (float*)(ws + 82560768);        //      1,024
  float*  part_l1   = (float*)(ws + 82561792);        //     14,068
  float*  part_l2   = (float*)(ws + 82575860);        //     14,068
  float*  part_conf = (float*)(ws + 82589928);        //      3,128
  unsigned short* W2pack = (unsigned short*)(ws + 82593056); // 32,768 B
  unsigned short* W1pack = (unsigned short*)(ws + 82625824); // 65,536 B
  (void)ws_size;

  float* out     = (float*)d_out;
  float* out_phi = out + 2;
  float* out_ec  = out + 480002;
  float* out_asg = out + 1080002;

  k_zero_out<<<(OUT_TOTAL + 255)/256, 256, 0, stream>>>(out, OUT_TOTAL);
  k_prep<<<8, 256, 0, stream>>>(W2, W2pack);
  k_prep_w1<<<16, 256, 0, stream>>>(W1, W1pack);

  for (int t = 0; t < T_ITERS; ++t){
    k_zero_agg<<<5000, 256, 0, stream>>>((float4*)agg);
    k_pq<<<N_VARS/32, 256, 0, stream>>>((t == 0) ? state0 : state, W1pack, PQ);
    k_edge<<<(2*N_EDGES)/32, 256, 0, stream>>>(PQ, W2pack, b1v, b2v, ln_g, ln_b, idxL, idxR, agg);
    k_stats<<<NB_STAT, 256, 0, stream>>>(agg, degrees, red_part);
    k_red<<<1, 256, 0, stream>>>(red_part, red);
    k_bn<<<N_VARS/4, 256, 0, stream>>>(agg, degrees, red, bn_g, bn_b, Wd, bd,
                                       state, asg, out_phi, out_asg, t);
  }
  k_conf<<<NB_CONF, 256, 0, stream>>>(asg, idxL, idxR, rel, out_ec, part_conf);
  k_fconf<<<1, 256, 0, stream>>>(part_conf, out);
  k_loss<<<NB_LOSS, 256, 0, stream>>>(out_phi, idxL, idxR, iLp, iRp, rel, confm, part_l1, part_l2);
  k_floss<<<1, 256, 0, stream>>>(part_l1, part_l2, out);
}

// Round 10
// 925.029 us; speedup vs baseline: 1.9325x; 1.0125x over previous
//
#include <hip/hip_runtime.h>
#include <math.h>

#define N_VARS 40000
#define FEAT 128
#define N_EDGES 200000
#define N_CONFP 100000
#define T_ITERS 3
#define EPSF 1e-5f

#define NB_CONF 782              // ceil(200000/256)
#define NB_LOSS 3517             // ceil(900000/256)
#define NB_STAT 157              // ceil(40000/256)
#define OUT_TOTAL 1120003
#define NCONF_SLOT 1120002       // sequential carve: 1+1+480000+600000+40000

typedef short short8 __attribute__((ext_vector_type(8)));
typedef float floatx4 __attribute__((ext_vector_type(4)));
typedef unsigned short ushort4v __attribute__((ext_vector_type(4)));

// integer-bit NaN/Inf scrub (immune to fast-math): NaN/Inf -> 0
__device__ __forceinline__ float scrub0(float x){
  unsigned u = __float_as_uint(x);
  return ((u & 0x7F800000u) == 0x7F800000u) ? 0.f : x;
}
// f32 -> bf16 bits, round-to-nearest-even
__device__ __forceinline__ unsigned short f2bf_rne(float x){
  unsigned u = __float_as_uint(x);
  u += 0x7FFFu + ((u >> 16) & 1u);
  return (unsigned short)(u >> 16);
}
// bf16 bits -> f32
__device__ __forceinline__ float bf2f(unsigned short h){
  return __uint_as_float(((unsigned)h) << 16);
}

// ---- zero entire float output buffer ----
__global__ __launch_bounds__(256) void k_zero_out(float* __restrict__ out, int n){
  int i = blockIdx.x*256 + threadIdx.x;
  if (i < n) out[i] = 0.f;
}
// ---- zero agg: 5000*256 float4 == N_VARS*FEAT floats exactly ----
__global__ __launch_bounds__(256) void k_zero_agg(float4* __restrict__ p){
  p[blockIdx.x*256 + threadIdx.x] = make_float4(0.f,0.f,0.f,0.f);
}

// ---- pack W2 (128x128 f32) into B-fragment-ordered bf16 (8 ntiles) ----
__global__ __launch_bounds__(256) void k_prep(const float* __restrict__ W2,
                                              unsigned short* __restrict__ W2pack){
  int gid = blockIdx.x*256 + threadIdx.x;   // 0..2047
  int lane = gid & 63;
  int ks = (gid >> 6) & 3;
  int ntg = gid >> 8;
  int kbase = ks*32 + (lane >> 4)*8;
  int n = ntg*16 + (lane & 15);
#pragma unroll
  for (int j = 0; j < 8; ++j)
    W2pack[gid*8 + j] = f2bf_rne(W2[(kbase + j)*FEAT + n]);
}

// ---- pack W1 (256x128 f32) into combined 128x256 B-fragment bf16 (16 ntiles) ----
__global__ __launch_bounds__(256) void k_prep_w1(const float* __restrict__ W1,
                                                 unsigned short* __restrict__ W1pack){
  int gid = blockIdx.x*256 + threadIdx.x;   // 0..4095
  int lane = gid & 63;
  int ks = (gid >> 6) & 3;
  int ntg = gid >> 8;                        // 0..15
  int kbase = ks*32 + (lane >> 4)*8;
  int n = ntg*16 + (lane & 15);
#pragma unroll
  for (int j = 0; j < 8; ++j){
    int k = kbase + j;
    float v = (n < 128) ? W1[k*FEAT + n] : W1[(128 + k)*FEAT + (n - 128)];
    W1pack[gid*8 + j] = f2bf_rne(v);
  }
}

// ---- PQ = x @ [W1top | W1bot]  (N x 256) via MFMA bf16 -> bf16 store ----
#define X_STRIDE 136
__global__ __launch_bounds__(256) void k_pq(const float* __restrict__ x,
                                            const unsigned short* __restrict__ W1pack,
                                            unsigned short* __restrict__ PQb){
  __shared__ __align__(16) unsigned short Xbf[32*X_STRIDE];
  const int tid = threadIdx.x;
  const int row0 = blockIdx.x * 32;
  const int c4 = (tid & 31)*4, g8 = tid >> 5;
#pragma unroll
  for (int r = 0; r < 4; ++r){
    int row = g8*4 + r;
    const float4 v = *(const float4*)&x[(row0 + row)*FEAT + c4];
    ushort4v u;
    u.x = f2bf_rne(v.x); u.y = f2bf_rne(v.y);
    u.z = f2bf_rne(v.z); u.w = f2bf_rne(v.w);
    *(ushort4v*)&Xbf[row*X_STRIDE + c4] = u;
  }
  __syncthreads();
  const int w = tid >> 6, lane = tid & 63;
  const int quad = lane >> 4, mcol = lane & 15;
#pragma unroll
  for (int mt = 0; mt < 2; ++mt){
    floatx4 a0 = {0.f,0.f,0.f,0.f};
    floatx4 a1 = {0.f,0.f,0.f,0.f};
    floatx4 a2 = {0.f,0.f,0.f,0.f};
    floatx4 a3 = {0.f,0.f,0.f,0.f};
#pragma unroll
    for (int ks = 0; ks < 4; ++ks){
      short8 a = *(const short8*)&Xbf[(mt*16 + mcol)*X_STRIDE + ks*32 + quad*8];
      const unsigned short* bp = W1pack + ((w*16 + ks)*64 + lane)*8;
      short8 b0 = *(const short8*)(bp);
      short8 b1 = *(const short8*)(bp + 2048);
      short8 b2 = *(const short8*)(bp + 4096);
      short8 b3 = *(const short8*)(bp + 6144);
      a0 = __builtin_amdgcn_mfma_f32_16x16x32_bf16(a, b0, a0, 0, 0, 0);
      a1 = __builtin_amdgcn_mfma_f32_16x16x32_bf16(a, b1, a1, 0, 0, 0);
      a2 = __builtin_amdgcn_mfma_f32_16x16x32_bf16(a, b2, a2, 0, 0, 0);
      a3 = __builtin_amdgcn_mfma_f32_16x16x32_bf16(a, b3, a3, 0, 0, 0);
    }
#pragma unroll
    for (int nt = 0; nt < 4; ++nt){
      floatx4 acc = (nt == 0) ? a0 : (nt == 1) ? a1 : (nt == 2) ? a2 : a3;
      int n = w*64 + nt*16 + mcol;
#pragma unroll
      for (int reg = 0; reg < 4; ++reg)
        PQb[(row0 + mt*16 + quad*4 + reg)*(2*FEAT) + n] = f2bf_rne(acc[reg]);
    }
  }
}

// ---- edge kernel: 32 messages/block, MFMA-bf16 U@W2, bf16 PQ gather ----
#define U_STRIDE 136   // bf16 elems
#define Z_STRIDE 132   // f32 elems
__global__ __launch_bounds__(256) void k_edge(const unsigned short* __restrict__ PQb,
    const unsigned short* __restrict__ W2pack, const float* __restrict__ b1v,
    const float* __restrict__ b2v, const float* __restrict__ ln_g, const float* __restrict__ ln_b,
    const int* __restrict__ idxL, const int* __restrict__ idxR,
    float* __restrict__ agg){
  __shared__ __align__(16) unsigned char smem[32*Z_STRIDE*4];  // 16896 B union
  unsigned short* Ubf = (unsigned short*)smem;                  // phase 1: 32*136 bf16
  float* sZ = (float*)smem;                                     // phase 2: 32*132 f32
  __shared__ int sTa[32], sTb[32];
  const int tid = threadIdx.x;
  const int m0 = blockIdx.x * 32;
  if (tid < 32){
    int m = m0 + tid;
    int e = (m < N_EDGES) ? m : (m - N_EDGES);
    int l = idxL[e], r = idxR[e];
    sTa[tid] = (m < N_EDGES) ? l : r;   // scatter target + Q row
    sTb[tid] = (m < N_EDGES) ? r : l;   // P row
  }
  __syncthreads();
  // stage U = relu(P[b] + Q[a] + b1) as bf16; 16B short8 gathers
  const int c8 = (tid & 15)*8, g16 = tid >> 4;
  const float4 b1a = *(const float4*)&b1v[c8];
  const float4 b1b = *(const float4*)&b1v[c8 + 4];
#pragma unroll
  for (int r = 0; r < 2; ++r){
    int row = r*16 + g16;
    short8 pb = *(const short8*)&PQb[sTb[row]*(2*FEAT) + c8];
    short8 qb = *(const short8*)&PQb[sTa[row]*(2*FEAT) + FEAT + c8];
    ushort4v u0, u1;
    u0.x = f2bf_rne(fmaxf(bf2f(pb[0]) + bf2f(qb[0]) + b1a.x, 0.f));
    u0.y = f2bf_rne(fmaxf(bf2f(pb[1]) + bf2f(qb[1]) + b1a.y, 0.f));
    u0.z = f2bf_rne(fmaxf(bf2f(pb[2]) + bf2f(qb[2]) + b1a.z, 0.f));
    u0.w = f2bf_rne(fmaxf(bf2f(pb[3]) + bf2f(qb[3]) + b1a.w, 0.f));
    u1.x = f2bf_rne(fmaxf(bf2f(pb[4]) + bf2f(qb[4]) + b1b.x, 0.f));
    u1.y = f2bf_rne(fmaxf(bf2f(pb[5]) + bf2f(qb[5]) + b1b.y, 0.f));
    u1.z = f2bf_rne(fmaxf(bf2f(pb[6]) + bf2f(qb[6]) + b1b.z, 0.f));
    u1.w = f2bf_rne(fmaxf(bf2f(pb[7]) + bf2f(qb[7]) + b1b.w, 0.f));
    *(ushort4v*)&Ubf[row*U_STRIDE + c8]     = u0;
    *(ushort4v*)&Ubf[row*U_STRIDE + c8 + 4] = u1;
  }
  __syncthreads();
  // MFMA: wave w -> mt = w&1 (rows), nhalf = w>>1 (cols nhalf*64..+63)
  const int w = tid >> 6, lane = tid & 63;
  const int mt = w & 1, nhalf = w >> 1;
  const int quad = lane >> 4, mcol = lane & 15;
  floatx4 acc0 = {0.f,0.f,0.f,0.f};
  floatx4 acc1 = {0.f,0.f,0.f,0.f};
  floatx4 acc2 = {0.f,0.f,0.f,0.f};
  floatx4 acc3 = {0.f,0.f,0.f,0.f};
#pragma unroll
  for (int ks = 0; ks < 4; ++ks){
    short8 a = *(const short8*)&Ubf[(mt*16 + mcol)*U_STRIDE + ks*32 + quad*8];
    const unsigned short* bp = W2pack + ((nhalf*4*256) + ks*64 + lane)*8;
    short8 bq0 = *(const short8*)(bp);
    short8 bq1 = *(const short8*)(bp + 2048);
    short8 bq2 = *(const short8*)(bp + 4096);
    short8 bq3 = *(const short8*)(bp + 6144);
    acc0 = __builtin_amdgcn_mfma_f32_16x16x32_bf16(a, bq0, acc0, 0, 0, 0);
    acc1 = __builtin_amdgcn_mfma_f32_16x16x32_bf16(a, bq1, acc1, 0, 0, 0);
    acc2 = __builtin_amdgcn_mfma_f32_16x16x32_bf16(a, bq2, acc2, 0, 0, 0);
    acc3 = __builtin_amdgcn_mfma_f32_16x16x32_bf16(a, bq3, acc3, 0, 0, 0);
  }
  __syncthreads();   // all Ubf reads complete before sZ overlays it
  // epilogue: Z = relu(acc + b2). D: row=quad*4+reg, col=lane&15
#pragma unroll
  for (int nt = 0; nt < 4; ++nt){
    floatx4 a4 = (nt == 0) ? acc0 : (nt == 1) ? acc1 : (nt == 2) ? acc2 : acc3;
    int n = nhalf*64 + nt*16 + mcol;
    float bb = b2v[n];
#pragma unroll
    for (int reg = 0; reg < 4; ++reg){
      int row = mt*16 + quad*4 + reg;
      sZ[row*Z_STRIDE + n] = fmaxf(a4[reg] + bb, 0.f);
    }
  }
  __syncthreads();
  // LN + scatter: wave wv handles rows wv*8 .. wv*8+7
  const int wv = tid >> 6, l = tid & 63;
  const float g0 = ln_g[l],  g1 = ln_g[l+64];
  const float be0 = ln_b[l], be1 = ln_b[l+64];
#pragma unroll
  for (int r8 = 0; r8 < 8; ++r8){
    int r = wv*8 + r8;
    float v0 = sZ[r*Z_STRIDE + l], v1 = sZ[r*Z_STRIDE + l + 64];
    float s = v0 + v1, q = v0*v0 + v1*v1;
#pragma unroll
    for (int o = 32; o > 0; o >>= 1){ s += __shfl_xor(s, o); q += __shfl_xor(q, o); }
    float mu = s * (1.f/FEAT);
    float var = fmaxf(q * (1.f/FEAT) - mu*mu, 0.f);
    float rv = rsqrtf(var + EPSF);
    int a = sTa[r];
    float o0 = scrub0(g0*(v0-mu)*rv + be0);
    float o1 = scrub0(g1*(v1-mu)*rv + be1);
    atomicAdd(&agg[a*FEAT + l],      o0);
    atomicAdd(&agg[a*FEAT + l + 64], o1);
  }
}

// ---- BN stats: per-block fp32 partial sum/sumsq of rec = agg/deg ----
__global__ __launch_bounds__(256) void k_stats(const float* __restrict__ agg,
    const float* __restrict__ degrees, float* __restrict__ red_part){
  const int tid = threadIdx.x;
  const int j = tid & 127, half_sel = tid >> 7;
  const int n0 = blockIdx.x * 256;
  float s1 = 0.f, s2 = 0.f;
  for (int i = half_sel; i < 256; i += 2){
    int n = n0 + i;
    if (n < N_VARS){
      float v = agg[n*FEAT + j] / degrees[n];
      s1 += v;
      s2 += v*v;
    }
  }
  __shared__ float sh1[256], sh2[256];
  sh1[tid] = s1; sh2[tid] = s2;
  __syncthreads();
  if (half_sel == 0){
    red_part[blockIdx.x*256 + j]       = sh1[tid] + sh1[tid+128];
    red_part[blockIdx.x*256 + 128 + j] = sh2[tid] + sh2[tid+128];
  }
}

// ---- reduce red_part -> red[256] (Kahan, single block, deterministic) ----
__global__ __launch_bounds__(256) void k_red(const float* __restrict__ red_part,
                                             float* __restrict__ red){
  const int tid = threadIdx.x;
  float s = 0.f, c = 0.f;
  for (int b = 0; b < NB_STAT; ++b){
    float y = red_part[b*256 + tid] - c;
    float t = s + y;
    c = (t - s) - y;
    s = t;
  }
  red[tid] = s;
}

// ---- BN apply + logits + softmax + argmax; one wave per row ----
__global__ __launch_bounds__(256) void k_bn(const float* __restrict__ agg,
    const float* __restrict__ degrees, const float* __restrict__ red,
    const float* __restrict__ bn_g, const float* __restrict__ bn_b,
    const float* __restrict__ Wd, const float* __restrict__ bd,
    float* __restrict__ state, int* __restrict__ asg,
    float* __restrict__ out_phi, float* __restrict__ out_asg, int t){
  const int w = threadIdx.x >> 6, l = threadIdx.x & 63;
  const int n = blockIdx.x*4 + w;
  const float invN = 1.f / (float)N_VARS;
  float mu0 = red[l]*invN,     mu1 = red[l+64]*invN;
  float v0  = fmaxf(red[128+l]*invN    - mu0*mu0, 0.f);
  float v1  = fmaxf(red[128+l+64]*invN - mu1*mu1, 0.f);
  float rv0 = rsqrtf(v0 + EPSF);
  float rv1 = rsqrtf(v1 + EPSF);
  float dinv = 1.f / degrees[n];
  float r0 = agg[n*FEAT + l]    * dinv;
  float r1 = agg[n*FEAT + l+64] * dinv;
  float s0 = scrub0(bn_g[l]   *(r0 - mu0)*rv0 + bn_b[l]);
  float s1 = scrub0(bn_g[l+64]*(r1 - mu1)*rv1 + bn_b[l+64]);
  state[n*FEAT + l]    = s0;
  state[n*FEAT + l+64] = s1;
  float p[4];
#pragma unroll
  for (int d = 0; d < 4; ++d)
    p[d] = s0*Wd[l*4 + d] + s1*Wd[(l+64)*4 + d];
#pragma unroll
  for (int o = 32; o > 0; o >>= 1){
#pragma unroll
    for (int d = 0; d < 4; ++d) p[d] += __shfl_xor(p[d], o);
  }
  if (l == 0){
    float lg[4];
#pragma unroll
    for (int d = 0; d < 4; ++d) lg[d] = scrub0(p[d] + bd[d]);
    float mx = fmaxf(fmaxf(lg[0],lg[1]), fmaxf(lg[2],lg[3]));
    float ex[4]; float ssum = 0.f;
#pragma unroll
    for (int d = 0; d < 4; ++d){ ex[d] = expf(lg[d] - mx); ssum += ex[d]; }
    float inv = 1.f / ssum;
    int am = 0; float bv = -1.f;
#pragma unroll
    for (int d = 0; d < 4; ++d){
      float pv = scrub0(ex[d]*inv);
      out_phi[n*12 + t*4 + d] = pv;
      if (pv > bv){ bv = pv; am = d; }
    }
    asg[n*3 + t] = am;
    if (t == 2) out_asg[n] = (float)am;
  }
}

// ---- edge conflicts -> out_ec + per-block partial of t=2 column ----
__global__ __launch_bounds__(256) void k_conf(const int* __restrict__ asg,
    const int* __restrict__ idxL, const int* __restrict__ idxR,
    const float* __restrict__ relation, float* __restrict__ out_ec,
    float* __restrict__ part_conf){
  const int e = blockIdx.x*256 + threadIdx.x;
  float c2 = 0.f;
  if (e < N_EDGES){
    int l = idxL[e], r = idxR[e];
#pragma unroll
    for (int tt = 0; tt < 3; ++tt){
      int ai = asg[l*3+tt] & 3, bi = asg[r*3+tt] & 3;
      float c = scrub0(1.f - relation[ai*4 + bi]);
      out_ec[e*3 + tt] = c;
      if (tt == 2) c2 = c;
    }
  }
  __shared__ float sh[256];
  sh[threadIdx.x] = c2;
  __syncthreads();
  for (int k = 128; k > 0; k >>= 1){
    if (threadIdx.x < k) sh[threadIdx.x] += sh[threadIdx.x + k];
    __syncthreads();
  }
  if (threadIdx.x == 0) part_conf[blockIdx.x] = sh[0];
}

// ---- final conflict reduce -> out[1], out[NCONF_SLOT] ----
__global__ __launch_bounds__(256) void k_fconf(const float* __restrict__ part_conf,
                                               float* __restrict__ out){
  const int tid = threadIdx.x;
  float s = 0.f;
  for (int i = tid; i < NB_CONF; i += 256) s += part_conf[i];
  __shared__ float sh[256];
  sh[tid] = s;
  __syncthreads();
  for (int k = 128; k > 0; k >>= 1){
    if (tid < k) sh[tid] += sh[tid + k];
    __syncthreads();
  }
  if (tid == 0){
    float nc = sh[0];
    out[NCONF_SLOT] = nc;
    out[1] = nc / (float)N_EDGES;
  }
}

// ---- pair losses from fp32 phi (in d_out): per-block partials ----
__global__ __launch_bounds__(256) void k_loss(const float* __restrict__ phi,
    const int* __restrict__ iL, const int* __restrict__ iR,
    const int* __restrict__ iLp, const int* __restrict__ iRp,
    const float* __restrict__ rel, const float* __restrict__ conf,
    float* __restrict__ part_l1, float* __restrict__ part_l2){
  const int m = blockIdx.x*256 + threadIdx.x;
  float p1 = 0.f, p2 = 0.f;
  if (m < N_EDGES*3){
    int e = m/3, tt = m - e*3;
    const float* pl = phi + iL[e]*12 + tt*4;
    const float* pr = phi + iR[e]*12 + tt*4;
    float s = 0.f;
#pragma unroll
    for (int j = 0; j < 4; ++j){
      float tj = 0.f;
#pragma unroll
      for (int i = 0; i < 4; ++i) tj += pl[i]*rel[i*4+j];
      s += tj*pr[j];
    }
    s = scrub0(s); s = fmaxf(s, 1e-35f);
    p1 = -logf(s);
  } else {
    int m2 = m - N_EDGES*3;
    if (m2 < N_CONFP*3){
      int e = m2/3, tt = m2 - e*3;
      const float* pl = phi + iLp[e]*12 + tt*4;
      const float* pr = phi + iRp[e]*12 + tt*4;
      float s = 0.f;
#pragma unroll
      for (int j = 0; j < 4; ++j){
        float tj = 0.f;
#pragma unroll
        for (int i = 0; i < 4; ++i) tj += pl[i]*conf[i*4+j];
        s += tj*pr[j];
      }
      s = scrub0(s); s = fmaxf(s, 1e-35f);
      p2 = -logf(s);
    }
  }
  __shared__ float sh1[256], sh2[256];
  sh1[threadIdx.x] = p1; sh2[threadIdx.x] = p2;
  __syncthreads();
  for (int k = 128; k > 0; k >>= 1){
    if (threadIdx.x < k){
      sh1[threadIdx.x] += sh1[threadIdx.x + k];
      sh2[threadIdx.x] += sh2[threadIdx.x + k];
    }
    __syncthreads();
  }
  if (threadIdx.x == 0){
    part_l1[blockIdx.x] = sh1[0];
    part_l2[blockIdx.x] = sh2[0];
  }
}

// ---- loss final reduce (Kahan) -> out[0] ----
__global__ __launch_bounds__(256) void k_floss(const float* __restrict__ part_l1,
    const float* __restrict__ part_l2, float* __restrict__ out){
  const int tid = threadIdx.x;
  float a = 0.f, ca = 0.f, b = 0.f, cb = 0.f;
  for (int i = tid; i < NB_LOSS; i += 256){
    float y = part_l1[i] - ca; float t = a + y; ca = (t - a) - y; a = t;
    float y2 = part_l2[i] - cb; float t2 = b + y2; cb = (t2 - b) - y2; b = t2;
  }
  __shared__ float sh1[256], sh2[256];
  sh1[tid] = a; sh2[tid] = b;
  __syncthreads();
  for (int k = 128; k > 0; k >>= 1){
    if (tid < k){ sh1[tid] += sh1[tid + k]; sh2[tid] += sh2[tid + k]; }
    __syncthreads();
  }
  if (tid == 0)
    out[0] = sh1[0]/(float)N_EDGES + sh2[0]/(10.f*(float)N_CONFP);
}

extern "C" void kernel_launch(void* const* d_in, const int* in_sizes, int n_in,
                              void* d_out, int out_size, void* d_ws, size_t ws_size,
                              hipStream_t stream){
  const float* state0  = (const float*)d_in[0];
  const float* W1      = (const float*)d_in[1];
  const float* b1v     = (const float*)d_in[2];
  const float* W2      = (const float*)d_in[3];
  const float* b2v     = (const float*)d_in[4];
  const float* ln_g    = (const float*)d_in[5];
  const float* ln_b    = (const float*)d_in[6];
  const float* bn_g    = (const float*)d_in[7];
  const float* bn_b    = (const float*)d_in[8];
  const float* Wd      = (const float*)d_in[9];
  const float* bd      = (const float*)d_in[10];
  const float* rel     = (const float*)d_in[11];
  const float* confm   = (const float*)d_in[12];
  const float* degrees = (const float*)d_in[13];
  const int* idxL = (const int*)d_in[14];
  const int* idxR = (const int*)d_in[15];
  const int* iLp  = (const int*)d_in[16];
  const int* iRp  = (const int*)d_in[17];

  char* ws = (char*)d_ws;
  float*  state     = (float*)(ws);                          // 20,480,000
  unsigned short* PQb = (unsigned short*)(ws + 20480000);    // 20,480,000 (N x 256 bf16)
  float*  agg       = (float*)(ws + 40960000);               // 20,480,000
  int*    asg       = (int*)  (ws + 61440000);               //    480,000
  float*  red_part  = (float*)(ws + 61920000);               //    160,768
  float*  red       = (float*)(ws + 62080768);               //      1,024
  float*  part_l1   = (float*)(ws + 62081792);               //     14,068
  float*  part_l2   = (float*)(ws + 62095860);               //     14,068
  float*  part_conf = (float*)(ws + 62109928);               //      3,128
  unsigned short* W2pack = (unsigned short*)(ws + 62113056); //     32,768
  unsigned short* W1pack = (unsigned short*)(ws + 62145824); //     65,536
  (void)ws_size;

  float* out     = (float*)d_out;
  float* out_phi = out + 2;
  float* out_ec  = out + 480002;
  float* out_asg = out + 1080002;

  k_zero_out<<<(OUT_TOTAL + 255)/256, 256, 0, stream>>>(out, OUT_TOTAL);
  k_prep<<<8, 256, 0, stream>>>(W2, W2pack);
  k_prep_w1<<<16, 256, 0, stream>>>(W1, W1pack);

  for (int t = 0; t < T_ITERS; ++t){
    k_zero_agg<<<5000, 256, 0, stream>>>((float4*)agg);
    k_pq<<<N_VARS/32, 256, 0, stream>>>((t == 0) ? state0 : state, W1pack, PQb);
    k_edge<<<(2*N_EDGES)/32, 256, 0, stream>>>(PQb, W2pack, b1v, b2v, ln_g, ln_b, idxL, idxR, agg);
    k_stats<<<NB_STAT, 256, 0, stream>>>(agg, degrees, red_part);
    k_red<<<1, 256, 0, stream>>>(red_part, red);
    k_bn<<<N_VARS/4, 256, 0, stream>>>(agg, degrees, red, bn_g, bn_b, Wd, bd,
                                       state, asg, out_phi, out_asg, t);
  }
  k_conf<<<NB_CONF, 256, 0, stream>>>(asg, idxL, idxR, rel, out_ec, part_conf);
  k_fconf<<<1, 256, 0, stream>>>(part_conf, out);
  k_loss<<<NB_LOSS, 256, 0, stream>>>(out_phi, idxL, idxR, iLp, iRp, rel, confm, part_l1, part_l2);
  k_floss<<<1, 256, 0, stream>>>(part_l1, part_l2, out);
}